// Round 1
// baseline (802.231 us; speedup 1.0000x reference)
//
#include <hip/hip_runtime.h>
#include <hip/hip_bf16.h>

// Problem: B=64, L=1024, ENC=1024, DEC=1024, ATT=1024
// M = B*L = 65536, K = ENC = 1024, N = ATT = 1024
//
// Pipeline:
//   ws: [W1T bf16 2MB][proj_h fp32 256KB][scores fp32 256KB]
//   1. memset scores = 0
//   2. transpose W1 (fp32 [K][N]) -> W1T (bf16 [N][K])
//   3. proj_h = hidden@W2 + W2_b + W1_b   (combined bias)
//   4. GEMM proj_f = feat@W1 (bf16 MFMA) fused epilogue:
//        scores[m] += sum_a tanh(proj_f + proj_h[b][a]) * V_w[a]  (atomic)
//   5. softmax over L -> alpha (d_out[0:65536])   (V_b cancels in softmax)
//   6. context[b][e] = sum_l alpha*feat -> d_out[65536:131072]

typedef __bf16 bf16x8 __attribute__((ext_vector_type(8)));
typedef float floatx4 __attribute__((ext_vector_type(4)));
typedef unsigned short ushort_t;
typedef unsigned long long u64;

__device__ __forceinline__ ushort_t f2b(float x) {
    union { float f; unsigned u; } v; v.f = x;
    // round-to-nearest-even fp32 -> bf16
    unsigned r = (v.u + 0x7fffu + ((v.u >> 16) & 1u)) >> 16;
    return (ushort_t)r;
}

// ---------------- W1 transpose + bf16 convert: [K][N] fp32 -> [N][K] bf16 ---
__global__ __launch_bounds__(256) void transpose_w1_kernel(
    const float* __restrict__ w1, ushort_t* __restrict__ w1t) {
    __shared__ ushort_t tile[64][65];
    const int k0 = blockIdx.x * 64, n0 = blockIdx.y * 64;
    const int tr = threadIdx.x >> 6;   // 0..3
    const int tc = threadIdx.x & 63;   // 0..63
#pragma unroll
    for (int i = 0; i < 16; i++) {
        int r = i * 4 + tr;
        tile[tc][r] = f2b(w1[(size_t)(k0 + r) * 1024 + n0 + tc]);
    }
    __syncthreads();
#pragma unroll
    for (int i = 0; i < 16; i++) {
        int r = i * 4 + tr;
        w1t[(size_t)(n0 + r) * 1024 + k0 + tc] = tile[r][tc];
    }
}

// ---------------- proj_h = hidden @ W2 + W2_b + W1_b ------------------------
__global__ __launch_bounds__(256) void projh_kernel(
    const float* __restrict__ hidden, const float* __restrict__ w2,
    const float* __restrict__ w2b, const float* __restrict__ w1b,
    float* __restrict__ ph) {
    const int b = blockIdx.y;
    const int a = blockIdx.x * 256 + threadIdx.x;
    const float* h = hidden + b * 1024;
    float sum = w2b[a] + w1b[a];
#pragma unroll 4
    for (int e = 0; e < 1024; e++)
        sum += h[e] * w2[(size_t)e * 1024 + a];
    ph[b * 1024 + a] = sum;
}

// ---------------- main GEMM + fused tanh-dot epilogue -----------------------
// tile 128x128, BK=64, 256 threads (4 waves, each 64x64 = 4x4 MFMA tiles)
#define KP 72   // BK + 8 pad (keeps 16B alignment for every row, 2-way-max conflicts)

__global__ __launch_bounds__(256) void gemm_scores_kernel(
    const float* __restrict__ feat,      // [M][1024] fp32
    const ushort_t* __restrict__ w1t,    // [N][1024] bf16
    const float* __restrict__ ph,        // [B][1024] combined bias
    const float* __restrict__ vw,        // [1024]
    float* __restrict__ scores) {        // [M] fp32, pre-zeroed, atomic
    __shared__ ushort_t As[128 * KP];
    __shared__ ushort_t Bs[128 * KP];
    __shared__ float cbias[128];
    __shared__ float vvw[128];

    const int tid = threadIdx.x;
    const int n0 = blockIdx.x * 128;
    const int m0 = blockIdx.y * 128;
    const int b  = m0 >> 10;             // L=1024, BM=128 -> one b per block

    if (tid < 128) {
        cbias[tid] = ph[(b << 10) + n0 + tid];
        vvw[tid]   = vw[n0 + tid];
    }

    const int wave = tid >> 6;
    const int lane = tid & 63;
    const int wr = (wave >> 1) * 64;     // wave row offset in tile
    const int wc = (wave & 1) * 64;      // wave col offset
    const int q  = lane >> 4;            // quad 0..3
    const int l15 = lane & 15;

    floatx4 acc[4][4] = {};

    // staging thread mapping
    const int arow = tid >> 4;           // 0..15
    const int acol = (tid & 15) * 4;     // 0..60
    const int brow = tid >> 3;           // 0..31
    const int bcol = (tid & 7) * 8;      // 0..56

    const float* aptr = feat + (size_t)m0 * 1024;
    const ushort_t* bptr = w1t + (size_t)n0 * 1024;

    for (int kt = 0; kt < 1024; kt += 64) {
        // A: 128 rows x 64 k fp32 -> bf16 in LDS [m][k]
#pragma unroll
        for (int p = 0; p < 8; p++) {
            int r = p * 16 + arow;
            const float4 f = *(const float4*)(aptr + (size_t)r * 1024 + kt + acol);
            u64 pack = (u64)f2b(f.x) | ((u64)f2b(f.y) << 16) |
                       ((u64)f2b(f.z) << 32) | ((u64)f2b(f.w) << 48);
            *(u64*)&As[r * KP + acol] = pack;
        }
        // B: 128 n-rows x 64 k bf16 (already [N][K]) -> LDS [n][k], 16B copies
#pragma unroll
        for (int p = 0; p < 4; p++) {
            int r = p * 32 + brow;
            *(uint4*)&Bs[r * KP + bcol] =
                *(const uint4*)(bptr + (size_t)r * 1024 + kt + bcol);
        }
        __syncthreads();
#pragma unroll
        for (int ks = 0; ks < 64; ks += 32) {
            bf16x8 af[4], bfr[4];
#pragma unroll
            for (int t = 0; t < 4; t++)
                af[t] = *(const bf16x8*)&As[(wr + t * 16 + l15) * KP + ks + q * 8];
#pragma unroll
            for (int t = 0; t < 4; t++)
                bfr[t] = *(const bf16x8*)&Bs[(wc + t * 16 + l15) * KP + ks + q * 8];
#pragma unroll
            for (int tm = 0; tm < 4; tm++)
#pragma unroll
                for (int tn = 0; tn < 4; tn++)
                    acc[tm][tn] = __builtin_amdgcn_mfma_f32_16x16x32_bf16(
                        af[tm], bfr[tn], acc[tm][tn], 0, 0, 0);
        }
        __syncthreads();
    }

    // Epilogue: C/D layout col=lane&15, row=quad*4+reg (measured m89/m91).
    // Per (tm,reg): quad q holds row tm*16+q*4+reg, its 16 lanes hold 16 cols.
#pragma unroll
    for (int tm = 0; tm < 4; tm++) {
#pragma unroll
        for (int r = 0; r < 4; r++) {
            const int row = wr + tm * 16 + q * 4 + r;
            float s = 0.f;
#pragma unroll
            for (int tn = 0; tn < 4; tn++) {
                const int col = wc + tn * 16 + l15;
                s += tanhf(acc[tm][tn][r] + cbias[col]) * vvw[col];
            }
            // reduce across the 16 lanes of the quad
            s += __shfl_xor(s, 1);
            s += __shfl_xor(s, 2);
            s += __shfl_xor(s, 4);
            s += __shfl_xor(s, 8);
            if (l15 == 0) atomicAdd(&scores[m0 + row], s);
        }
    }
}

// ---------------- softmax over L per b --------------------------------------
__global__ __launch_bounds__(256) void softmax_kernel(
    const float* __restrict__ scores, float* __restrict__ alpha) {
    const int b = blockIdx.x;
    const int tid = threadIdx.x;
    __shared__ float red[256];
    float v[4];
    float mx = -1e30f;
#pragma unroll
    for (int i = 0; i < 4; i++) {
        v[i] = scores[b * 1024 + tid + i * 256];
        mx = fmaxf(mx, v[i]);
    }
    red[tid] = mx; __syncthreads();
    for (int s = 128; s > 0; s >>= 1) {
        if (tid < s) red[tid] = fmaxf(red[tid], red[tid + s]);
        __syncthreads();
    }
    mx = red[0]; __syncthreads();
    float sum = 0.f;
#pragma unroll
    for (int i = 0; i < 4; i++) { v[i] = __expf(v[i] - mx); sum += v[i]; }
    red[tid] = sum; __syncthreads();
    for (int s = 128; s > 0; s >>= 1) {
        if (tid < s) red[tid] += red[tid + s];
        __syncthreads();
    }
    const float inv = 1.0f / red[0];
#pragma unroll
    for (int i = 0; i < 4; i++)
        alpha[b * 1024 + tid + i * 256] = v[i] * inv;
}

// ---------------- context = alpha^T @ features ------------------------------
__global__ __launch_bounds__(256) void context_kernel(
    const float* __restrict__ alpha, const float* __restrict__ feat,
    float* __restrict__ ctx) {
    const int b = blockIdx.y;
    const int e = blockIdx.x * 64 + (threadIdx.x & 63);
    const int ls = threadIdx.x >> 6;         // 0..3, splits L
    const float* fb = feat + (size_t)b * 1024 * 1024;
    const float* ab = alpha + b * 1024;
    float acc = 0.f;
    const int l0 = ls * 256;
#pragma unroll 4
    for (int l = l0; l < l0 + 256; l++)
        acc += ab[l] * fb[(size_t)l * 1024 + e];
    __shared__ float red[256];
    red[threadIdx.x] = acc; __syncthreads();
    if (threadIdx.x < 64)
        ctx[b * 1024 + e] = red[threadIdx.x] + red[threadIdx.x + 64] +
                            red[threadIdx.x + 128] + red[threadIdx.x + 192];
}

// ---------------- launcher --------------------------------------------------
extern "C" void kernel_launch(void* const* d_in, const int* in_sizes, int n_in,
                              void* d_out, int out_size, void* d_ws, size_t ws_size,
                              hipStream_t stream) {
    const float* feat = (const float*)d_in[0];   // [64,1024,1024]
    const float* hid  = (const float*)d_in[1];   // [64,1024]
    const float* w1w  = (const float*)d_in[2];   // [1024,1024]
    const float* w1b  = (const float*)d_in[3];   // [1024]
    const float* w2w  = (const float*)d_in[4];   // [1024,1024]
    const float* w2b  = (const float*)d_in[5];   // [1024]
    const float* vw   = (const float*)d_in[6];   // [1024]
    // d_in[7] = V_b: constant shift, cancels in softmax -> unused

    const size_t W1T_BYTES = (size_t)1024 * 1024 * 2;   // 2 MB
    const size_t PH_BYTES  = (size_t)64 * 1024 * 4;     // 256 KB
    const size_t SC_BYTES  = (size_t)64 * 1024 * 4;     // 256 KB
    if (ws_size < W1T_BYTES + PH_BYTES + SC_BYTES) return;

    char* ws = (char*)d_ws;
    ushort_t* w1t  = (ushort_t*)ws;
    float* ph      = (float*)(ws + W1T_BYTES);
    float* scores  = (float*)(ws + W1T_BYTES + PH_BYTES);

    float* alpha = (float*)d_out;           // [64,1024]
    float* ctx   = alpha + 64 * 1024;       // [64,1024]

    hipMemsetAsync(scores, 0, SC_BYTES, stream);
    transpose_w1_kernel<<<dim3(16, 16), 256, 0, stream>>>(w1w, w1t);
    projh_kernel<<<dim3(4, 64), 256, 0, stream>>>(hid, w2w, w2b, w1b, ph);
    gemm_scores_kernel<<<dim3(8, 512), 256, 0, stream>>>(feat, w1t, ph, vw, scores);
    softmax_kernel<<<64, 256, 0, stream>>>(scores, alpha);
    context_kernel<<<dim3(16, 64), 256, 0, stream>>>(alpha, feat, ctx);
}

// Round 2
// 784.583 us; speedup vs baseline: 1.0225x; 1.0225x over previous
//
#include <hip/hip_runtime.h>
#include <hip/hip_bf16.h>

// Problem: B=64, L=1024, ENC=1024, DEC=1024, ATT=1024
// M = B*L = 65536, K = ENC = 1024, N = ATT = 1024
//
// Pipeline (fast path, needs ~137 MB ws):
//   ws: [featb bf16 128MB][W1T bf16 2MB][proj_h fp32 256KB][scores fp32 256KB]
//   1. memset scores = 0
//   2. convert features fp32 -> bf16 (featb)
//   3. transpose W1 (fp32 [K][N]) -> W1T (bf16 [N][K])
//   4. proj_h = hidden@W2 + W2_b + W1_b   (combined bias)
//   5. GEMM proj_f = featb@W1T (bf16 MFMA, global_load_lds staging) fused:
//        scores[m] += sum_a tanh(proj_f + proj_h[b][a]) * V_w[a]  (atomic)
//   6. softmax over L -> alpha (d_out[0:65536])   (V_b cancels in softmax)
//   7. context[b][e] = sum_l alpha*feat (fp32 feat for accuracy)

typedef __bf16 bf16x8 __attribute__((ext_vector_type(8)));
typedef float floatx4 __attribute__((ext_vector_type(4)));
typedef unsigned short ushort_t;
typedef unsigned long long u64;

__device__ __forceinline__ ushort_t f2b(float x) {
    union { float f; unsigned u; } v; v.f = x;
    unsigned r = (v.u + 0x7fffu + ((v.u >> 16) & 1u)) >> 16;  // RNE
    return (ushort_t)r;
}

__device__ __forceinline__ u64 pack4(float4 f) {
    return (u64)f2b(f.x) | ((u64)f2b(f.y) << 16) |
           ((u64)f2b(f.z) << 32) | ((u64)f2b(f.w) << 48);
}

__device__ __forceinline__ void gload_lds16(const void* g, void* l) {
    __builtin_amdgcn_global_load_lds(
        (const __attribute__((address_space(1))) void*)g,
        (__attribute__((address_space(3))) void*)l, 16, 0, 0);
}

// ---------------- features fp32 -> bf16 -------------------------------------
__global__ __launch_bounds__(256) void convert_feat_kernel(
    const float* __restrict__ feat, ushort_t* __restrict__ featb) {
    const size_t idx = ((size_t)blockIdx.x * 256 + threadIdx.x) * 8;
    const float4 f0 = *(const float4*)(feat + idx);
    const float4 f1 = *(const float4*)(feat + idx + 4);
    *(u64*)(featb + idx)     = pack4(f0);
    *(u64*)(featb + idx + 4) = pack4(f1);
}

// ---------------- W1 transpose + bf16 convert: [K][N] fp32 -> [N][K] bf16 ---
__global__ __launch_bounds__(256) void transpose_w1_kernel(
    const float* __restrict__ w1, ushort_t* __restrict__ w1t) {
    __shared__ ushort_t tile[64][65];
    const int k0 = blockIdx.x * 64, n0 = blockIdx.y * 64;
    const int tr = threadIdx.x >> 6;   // 0..3
    const int tc = threadIdx.x & 63;   // 0..63
#pragma unroll
    for (int i = 0; i < 16; i++) {
        int r = i * 4 + tr;
        tile[tc][r] = f2b(w1[(size_t)(k0 + r) * 1024 + n0 + tc]);
    }
    __syncthreads();
#pragma unroll
    for (int i = 0; i < 16; i++) {
        int r = i * 4 + tr;
        w1t[(size_t)(n0 + r) * 1024 + k0 + tc] = tile[r][tc];
    }
}

// ---------------- proj_h = hidden @ W2 + W2_b + W1_b ------------------------
__global__ __launch_bounds__(256) void projh_kernel(
    const float* __restrict__ hidden, const float* __restrict__ w2,
    const float* __restrict__ w2b, const float* __restrict__ w1b,
    float* __restrict__ ph) {
    const int b = blockIdx.y;
    const int a = blockIdx.x * 256 + threadIdx.x;
    const float* h = hidden + b * 1024;
    float sum = w2b[a] + w1b[a];
#pragma unroll 8
    for (int e = 0; e < 1024; e++)
        sum += h[e] * w2[(size_t)e * 1024 + a];
    ph[b * 1024 + a] = sum;
}

// ---------------- main GEMM (m97 structure) + fused tanh-dot epilogue -------
// tile 128x128, BK=64, 256 threads (4 waves, each 64x64 = 4x4 MFMA tiles)
// LDS: un-padded [128][64] bf16 (global_load_lds requires lane-contiguous)
__global__ __launch_bounds__(256) void gemm_scores_bf16_kernel(
    const ushort_t* __restrict__ featb,  // [M][1024] bf16
    const ushort_t* __restrict__ w1t,    // [N][1024] bf16
    const float* __restrict__ ph,        // [B][1024] combined bias
    const float* __restrict__ vw,        // [1024]
    float* __restrict__ scores) {        // [M] fp32, pre-zeroed, atomic
    __shared__ ushort_t As[128 * 64];
    __shared__ ushort_t Bs[128 * 64];
    __shared__ float cbias[128];
    __shared__ float vvw[128];

    const int tid = threadIdx.x;
    const int n0 = blockIdx.x * 128;
    const int m0 = blockIdx.y * 128;
    const int b  = m0 >> 10;             // L=1024, BM=128 -> one b per block

    if (tid < 128) {
        cbias[tid] = ph[(b << 10) + n0 + tid];
        vvw[tid]   = vw[n0 + tid];
    }

    const int wave = tid >> 6;
    const int lane = tid & 63;
    const int wr = (wave >> 1) * 64;
    const int wc = (wave & 1) * 64;
    const int q  = lane >> 4;
    const int l15 = lane & 15;

    floatx4 acc[4][4] = {};

    // global_load_lds staging: lane i of a wave-segment covers
    // row seg*8 + (i>>3), bf16 cols (i&7)*8 .. +7  (16 B), LDS contiguous.
    const int srow = lane >> 3;          // 0..7
    const int scol = (lane & 7) * 8;     // 0..56

    const ushort_t* aBase = featb + (size_t)m0 * 1024;
    const ushort_t* bBase = w1t  + (size_t)n0 * 1024;

    for (int kt = 0; kt < 1024; kt += 64) {
#pragma unroll
        for (int p = 0; p < 4; p++) {
            const int seg = wave * 4 + p;            // 0..15
            const int row = seg * 8 + srow;
            gload_lds16(aBase + (size_t)row * 1024 + kt + scol, As + seg * 512);
            gload_lds16(bBase + (size_t)row * 1024 + kt + scol, Bs + seg * 512);
        }
        __syncthreads();
#pragma unroll
        for (int ks = 0; ks < 64; ks += 32) {
            bf16x8 af[4], bfr[4];
#pragma unroll
            for (int t = 0; t < 4; t++)
                af[t] = *(const bf16x8*)&As[(wr + t * 16 + l15) * 64 + ks + q * 8];
#pragma unroll
            for (int t = 0; t < 4; t++)
                bfr[t] = *(const bf16x8*)&Bs[(wc + t * 16 + l15) * 64 + ks + q * 8];
#pragma unroll
            for (int tm = 0; tm < 4; tm++)
#pragma unroll
                for (int tn = 0; tn < 4; tn++)
                    acc[tm][tn] = __builtin_amdgcn_mfma_f32_16x16x32_bf16(
                        af[tm], bfr[tn], acc[tm][tn], 0, 0, 0);
        }
        __syncthreads();
    }

    // Epilogue: C/D layout col=lane&15, row=quad*4+reg (measured m89/m91).
#pragma unroll
    for (int tm = 0; tm < 4; tm++) {
#pragma unroll
        for (int r = 0; r < 4; r++) {
            const int row = wr + tm * 16 + q * 4 + r;
            float s = 0.f;
#pragma unroll
            for (int tn = 0; tn < 4; tn++) {
                const int col = wc + tn * 16 + l15;
                s += tanhf(acc[tm][tn][r] + cbias[col]) * vvw[col];
            }
            s += __shfl_xor(s, 1);
            s += __shfl_xor(s, 2);
            s += __shfl_xor(s, 4);
            s += __shfl_xor(s, 8);
            if (l15 == 0) atomicAdd(&scores[m0 + row], s);
        }
    }
}

// ---------------- fallback GEMM (fp32 A staging, round-1) -------------------
#define KP 72
__global__ __launch_bounds__(256) void gemm_scores_f32_kernel(
    const float* __restrict__ feat, const ushort_t* __restrict__ w1t,
    const float* __restrict__ ph, const float* __restrict__ vw,
    float* __restrict__ scores) {
    __shared__ ushort_t As[128 * KP];
    __shared__ ushort_t Bs[128 * KP];
    __shared__ float cbias[128];
    __shared__ float vvw[128];
    const int tid = threadIdx.x;
    const int n0 = blockIdx.x * 128, m0 = blockIdx.y * 128;
    const int b = m0 >> 10;
    if (tid < 128) { cbias[tid] = ph[(b << 10) + n0 + tid]; vvw[tid] = vw[n0 + tid]; }
    const int wave = tid >> 6, lane = tid & 63;
    const int wr = (wave >> 1) * 64, wc = (wave & 1) * 64;
    const int q = lane >> 4, l15 = lane & 15;
    floatx4 acc[4][4] = {};
    const int arow = tid >> 4, acol = (tid & 15) * 4;
    const int brow = tid >> 3, bcol = (tid & 7) * 8;
    const float* aptr = feat + (size_t)m0 * 1024;
    const ushort_t* bptr = w1t + (size_t)n0 * 1024;
    for (int kt = 0; kt < 1024; kt += 64) {
#pragma unroll
        for (int p = 0; p < 8; p++) {
            int r = p * 16 + arow;
            const float4 f = *(const float4*)(aptr + (size_t)r * 1024 + kt + acol);
            *(u64*)&As[r * KP + acol] = pack4(f);
        }
#pragma unroll
        for (int p = 0; p < 4; p++) {
            int r = p * 32 + brow;
            *(uint4*)&Bs[r * KP + bcol] =
                *(const uint4*)(bptr + (size_t)r * 1024 + kt + bcol);
        }
        __syncthreads();
#pragma unroll
        for (int ks = 0; ks < 64; ks += 32) {
            bf16x8 af[4], bfr[4];
#pragma unroll
            for (int t = 0; t < 4; t++)
                af[t] = *(const bf16x8*)&As[(wr + t * 16 + l15) * KP + ks + q * 8];
#pragma unroll
            for (int t = 0; t < 4; t++)
                bfr[t] = *(const bf16x8*)&Bs[(wc + t * 16 + l15) * KP + ks + q * 8];
#pragma unroll
            for (int tm = 0; tm < 4; tm++)
#pragma unroll
                for (int tn = 0; tn < 4; tn++)
                    acc[tm][tn] = __builtin_amdgcn_mfma_f32_16x16x32_bf16(
                        af[tm], bfr[tn], acc[tm][tn], 0, 0, 0);
        }
        __syncthreads();
    }
#pragma unroll
    for (int tm = 0; tm < 4; tm++) {
#pragma unroll
        for (int r = 0; r < 4; r++) {
            const int row = wr + tm * 16 + q * 4 + r;
            float s = 0.f;
#pragma unroll
            for (int tn = 0; tn < 4; tn++) {
                const int col = wc + tn * 16 + l15;
                s += tanhf(acc[tm][tn][r] + cbias[col]) * vvw[col];
            }
            s += __shfl_xor(s, 1);
            s += __shfl_xor(s, 2);
            s += __shfl_xor(s, 4);
            s += __shfl_xor(s, 8);
            if (l15 == 0) atomicAdd(&scores[m0 + row], s);
        }
    }
}

// ---------------- softmax over L per b --------------------------------------
__global__ __launch_bounds__(256) void softmax_kernel(
    const float* __restrict__ scores, float* __restrict__ alpha) {
    const int b = blockIdx.x;
    const int tid = threadIdx.x;
    __shared__ float red[256];
    float v[4];
    float mx = -1e30f;
#pragma unroll
    for (int i = 0; i < 4; i++) {
        v[i] = scores[b * 1024 + tid + i * 256];
        mx = fmaxf(mx, v[i]);
    }
    red[tid] = mx; __syncthreads();
    for (int s = 128; s > 0; s >>= 1) {
        if (tid < s) red[tid] = fmaxf(red[tid], red[tid + s]);
        __syncthreads();
    }
    mx = red[0]; __syncthreads();
    float sum = 0.f;
#pragma unroll
    for (int i = 0; i < 4; i++) { v[i] = __expf(v[i] - mx); sum += v[i]; }
    red[tid] = sum; __syncthreads();
    for (int s = 128; s > 0; s >>= 1) {
        if (tid < s) red[tid] += red[tid + s];
        __syncthreads();
    }
    const float inv = 1.0f / red[0];
#pragma unroll
    for (int i = 0; i < 4; i++)
        alpha[b * 1024 + tid + i * 256] = v[i] * inv;
}

// ---------------- context = alpha^T @ features (fp32 feat) ------------------
__global__ __launch_bounds__(256) void context_kernel(
    const float* __restrict__ alpha, const float* __restrict__ feat,
    float* __restrict__ ctx) {
    const int b = blockIdx.y;
    const int e = blockIdx.x * 64 + (threadIdx.x & 63);
    const int ls = threadIdx.x >> 6;
    const float* fb = feat + (size_t)b * 1024 * 1024;
    const float* ab = alpha + b * 1024;
    float acc = 0.f;
    const int l0 = ls * 256;
#pragma unroll 4
    for (int l = l0; l < l0 + 256; l++)
        acc += ab[l] * fb[(size_t)l * 1024 + e];
    __shared__ float red[256];
    red[threadIdx.x] = acc; __syncthreads();
    if (threadIdx.x < 64)
        ctx[b * 1024 + e] = red[threadIdx.x] + red[threadIdx.x + 64] +
                            red[threadIdx.x + 128] + red[threadIdx.x + 192];
}

// ---------------- launcher --------------------------------------------------
extern "C" void kernel_launch(void* const* d_in, const int* in_sizes, int n_in,
                              void* d_out, int out_size, void* d_ws, size_t ws_size,
                              hipStream_t stream) {
    const float* feat = (const float*)d_in[0];   // [64,1024,1024]
    const float* hid  = (const float*)d_in[1];   // [64,1024]
    const float* w1w  = (const float*)d_in[2];   // [1024,1024]
    const float* w1b  = (const float*)d_in[3];   // [1024]
    const float* w2w  = (const float*)d_in[4];   // [1024,1024]
    const float* w2b  = (const float*)d_in[5];   // [1024]
    const float* vw   = (const float*)d_in[6];   // [1024]
    // d_in[7] = V_b: cancels in softmax -> unused

    const size_t FEATB_BYTES = (size_t)64 * 1024 * 1024 * 2;  // 128 MB
    const size_t W1T_BYTES   = (size_t)1024 * 1024 * 2;       // 2 MB
    const size_t PH_BYTES    = (size_t)64 * 1024 * 4;         // 256 KB
    const size_t SC_BYTES    = (size_t)64 * 1024 * 4;         // 256 KB
    const bool   big_ws = ws_size >= FEATB_BYTES + W1T_BYTES + PH_BYTES + SC_BYTES;
    if (!big_ws && ws_size < W1T_BYTES + PH_BYTES + SC_BYTES) return;

    char* ws = (char*)d_ws;
    ushort_t* featb = (ushort_t*)ws;
    size_t off = big_ws ? FEATB_BYTES : 0;
    ushort_t* w1t  = (ushort_t*)(ws + off);
    float* ph      = (float*)(ws + off + W1T_BYTES);
    float* scores  = (float*)(ws + off + W1T_BYTES + PH_BYTES);

    float* alpha = (float*)d_out;           // [64,1024]
    float* ctx   = alpha + 64 * 1024;       // [64,1024]

    hipMemsetAsync(scores, 0, SC_BYTES, stream);
    transpose_w1_kernel<<<dim3(16, 16), 256, 0, stream>>>(w1w, w1t);
    projh_kernel<<<dim3(4, 64), 256, 0, stream>>>(hid, w2w, w2b, w1b, ph);
    if (big_ws) {
        convert_feat_kernel<<<32768, 256, 0, stream>>>(feat, featb);
        gemm_scores_bf16_kernel<<<dim3(8, 512), 256, 0, stream>>>(
            featb, w1t, ph, vw, scores);
    } else {
        gemm_scores_f32_kernel<<<dim3(8, 512), 256, 0, stream>>>(
            feat, w1t, ph, vw, scores);
    }
    softmax_kernel<<<64, 256, 0, stream>>>(scores, alpha);
    context_kernel<<<dim3(16, 64), 256, 0, stream>>>(alpha, feat, ctx);
}

// Round 3
// 717.736 us; speedup vs baseline: 1.1177x; 1.0931x over previous
//
#include <hip/hip_runtime.h>
#include <hip/hip_bf16.h>

// Problem: B=64, L=1024, ENC=1024, DEC=1024, ATT=1024
// M = B*L = 65536, K = ENC = 1024, N = ATT = 1024
//
// Pipeline (fast path, needs ~137 MB ws):
//   ws: [featb bf16 128MB][W1T bf16 2MB][proj_h fp32 256KB][scores fp32 256KB]
//   1. memset scores = 0
//   2. convert features fp32 -> bf16 (featb)
//   3. transpose W1 (fp32 [K][N]) -> W1T (bf16 [N][K])
//   4. proj_h = hidden@W2 + W2_b + W1_b   (combined bias)
//   5. GEMM proj_f = featb@W1T (bf16 MFMA, global_load_lds staging,
//      XOR-swizzled LDS to kill the 16-way b128 bank conflicts) fused:
//        scores[m] += sum_a tanh(proj_f + proj_h[b][a]) * V_w[a]  (atomic)
//   6. softmax over L -> alpha (d_out[0:65536])   (V_b cancels in softmax)
//   7. context[b][e] = sum_l alpha*feat (fp32 feat for accuracy, float4 loads)

typedef __bf16 bf16x8 __attribute__((ext_vector_type(8)));
typedef float floatx4 __attribute__((ext_vector_type(4)));
typedef unsigned short ushort_t;
typedef unsigned long long u64;

__device__ __forceinline__ ushort_t f2b(float x) {
    union { float f; unsigned u; } v; v.f = x;
    unsigned r = (v.u + 0x7fffu + ((v.u >> 16) & 1u)) >> 16;  // RNE
    return (ushort_t)r;
}

__device__ __forceinline__ u64 pack4(float4 f) {
    return (u64)f2b(f.x) | ((u64)f2b(f.y) << 16) |
           ((u64)f2b(f.z) << 32) | ((u64)f2b(f.w) << 48);
}

__device__ __forceinline__ void gload_lds16(const void* g, void* l) {
    __builtin_amdgcn_global_load_lds(
        (const __attribute__((address_space(1))) void*)g,
        (__attribute__((address_space(3))) void*)l, 16, 0, 0);
}

// ---------------- features fp32 -> bf16 -------------------------------------
__global__ __launch_bounds__(256) void convert_feat_kernel(
    const float* __restrict__ feat, ushort_t* __restrict__ featb) {
    const size_t idx = ((size_t)blockIdx.x * 256 + threadIdx.x) * 8;
    const float4 f0 = *(const float4*)(feat + idx);
    const float4 f1 = *(const float4*)(feat + idx + 4);
    *(u64*)(featb + idx)     = pack4(f0);
    *(u64*)(featb + idx + 4) = pack4(f1);
}

// ---------------- W1 transpose + bf16 convert: [K][N] fp32 -> [N][K] bf16 ---
__global__ __launch_bounds__(256) void transpose_w1_kernel(
    const float* __restrict__ w1, ushort_t* __restrict__ w1t) {
    __shared__ ushort_t tile[64][65];
    const int k0 = blockIdx.x * 64, n0 = blockIdx.y * 64;
    const int tr = threadIdx.x >> 6;   // 0..3
    const int tc = threadIdx.x & 63;   // 0..63
#pragma unroll
    for (int i = 0; i < 16; i++) {
        int r = i * 4 + tr;
        tile[tc][r] = f2b(w1[(size_t)(k0 + r) * 1024 + n0 + tc]);
    }
    __syncthreads();
#pragma unroll
    for (int i = 0; i < 16; i++) {
        int r = i * 4 + tr;
        w1t[(size_t)(n0 + r) * 1024 + k0 + tc] = tile[r][tc];
    }
}

// ---------------- proj_h = hidden @ W2 + W2_b + W1_b ------------------------
// grid (16, 64): x = 64-wide a-chunk, y = b. 256 thr = 64 a x 4 e-groups.
__global__ __launch_bounds__(256) void projh_kernel(
    const float* __restrict__ hidden, const float* __restrict__ w2,
    const float* __restrict__ w2b, const float* __restrict__ w1b,
    float* __restrict__ ph) {
    const int b  = blockIdx.y;
    const int al = threadIdx.x & 63;
    const int eg = threadIdx.x >> 6;            // 0..3
    const int a  = blockIdx.x * 64 + al;
    const float* h = hidden + b * 1024;
    float sum = 0.f;
    const int e0 = eg * 256;
#pragma unroll 8
    for (int e = e0; e < e0 + 256; e++)
        sum += h[e] * w2[(size_t)e * 1024 + a];
    __shared__ float red[256];
    red[threadIdx.x] = sum;
    __syncthreads();
    if (threadIdx.x < 64)
        ph[b * 1024 + a] = w2b[a] + w1b[a] + red[al] + red[al + 64] +
                           red[al + 128] + red[al + 192];
}

// ---------------- main GEMM (m97 structure + XOR swizzle) -------------------
// tile 128x128, BK=64, 256 threads (4 waves, each 64x64 = 4x4 MFMA tiles)
// LDS rows are 8 x 16B blocks; block b of row r holds global block b^(r&7).
__global__ __launch_bounds__(256) void gemm_scores_bf16_kernel(
    const ushort_t* __restrict__ featb,  // [M][1024] bf16
    const ushort_t* __restrict__ w1t,    // [N][1024] bf16
    const float* __restrict__ ph,        // [B][1024] combined bias
    const float* __restrict__ vw,        // [1024]
    float* __restrict__ scores) {        // [M] fp32, pre-zeroed, atomic
    __shared__ ushort_t As[128 * 64];
    __shared__ ushort_t Bs[128 * 64];
    __shared__ float cbias[128];
    __shared__ float vvw[128];

    const int tid = threadIdx.x;
    const int n0 = blockIdx.x * 128;
    const int m0 = blockIdx.y * 128;
    const int b  = m0 >> 10;             // L=1024, BM=128 -> one b per block

    if (tid < 128) {
        cbias[tid] = ph[(b << 10) + n0 + tid];
        vvw[tid]   = vw[n0 + tid];
    }

    const int wave = tid >> 6;
    const int lane = tid & 63;
    const int wr = (wave >> 1) * 64;
    const int wc = (wave & 1) * 64;
    const int q  = lane >> 4;
    const int l15 = lane & 15;

    floatx4 acc[4][4] = {};

    // staging: lane i -> LDS row seg*8+(i>>3), LDS block i&7;
    // global block loaded = (i&7)^(i>>3)  => LDS blk b holds glob blk b^(r&7)
    const int srow = lane >> 3;                          // 0..7
    const int scol = ((lane & 7) ^ srow) << 3;           // swizzled, x8 ushorts

    const ushort_t* aBase = featb + (size_t)m0 * 1024;
    const ushort_t* bBase = w1t  + (size_t)n0 * 1024;

    for (int kt = 0; kt < 1024; kt += 64) {
#pragma unroll
        for (int p = 0; p < 4; p++) {
            const int seg = wave * 4 + p;            // 0..15
            const int row = seg * 8 + srow;
            gload_lds16(aBase + (size_t)row * 1024 + kt + scol, As + seg * 512);
            gload_lds16(bBase + (size_t)row * 1024 + kt + scol, Bs + seg * 512);
        }
        __syncthreads();
#pragma unroll
        for (int ks = 0; ks < 64; ks += 32) {
            bf16x8 af[4], bfr[4];
#pragma unroll
            for (int t = 0; t < 4; t++) {
                const int r = wr + t * 16 + l15;
                const int g = (ks >> 3) + q;         // global 16B-block 0..7
                af[t] = *(const bf16x8*)&As[r * 64 + ((g ^ (r & 7)) << 3)];
            }
#pragma unroll
            for (int t = 0; t < 4; t++) {
                const int r = wc + t * 16 + l15;
                const int g = (ks >> 3) + q;
                bfr[t] = *(const bf16x8*)&Bs[r * 64 + ((g ^ (r & 7)) << 3)];
            }
#pragma unroll
            for (int tm = 0; tm < 4; tm++)
#pragma unroll
                for (int tn = 0; tn < 4; tn++)
                    acc[tm][tn] = __builtin_amdgcn_mfma_f32_16x16x32_bf16(
                        af[tm], bfr[tn], acc[tm][tn], 0, 0, 0);
        }
        __syncthreads();
    }

    // Epilogue: C/D layout col=lane&15, row=quad*4+reg (measured m89/m91).
#pragma unroll
    for (int tm = 0; tm < 4; tm++) {
#pragma unroll
        for (int r = 0; r < 4; r++) {
            const int row = wr + tm * 16 + q * 4 + r;
            float s = 0.f;
#pragma unroll
            for (int tn = 0; tn < 4; tn++) {
                const int col = wc + tn * 16 + l15;
                s += tanhf(acc[tm][tn][r] + cbias[col]) * vvw[col];
            }
            s += __shfl_xor(s, 1);
            s += __shfl_xor(s, 2);
            s += __shfl_xor(s, 4);
            s += __shfl_xor(s, 8);
            if (l15 == 0) atomicAdd(&scores[m0 + row], s);
        }
    }
}

// ---------------- softmax over L per b --------------------------------------
__global__ __launch_bounds__(256) void softmax_kernel(
    const float* __restrict__ scores, float* __restrict__ alpha) {
    const int b = blockIdx.x;
    const int tid = threadIdx.x;
    __shared__ float red[256];
    float v[4];
    float mx = -1e30f;
#pragma unroll
    for (int i = 0; i < 4; i++) {
        v[i] = scores[b * 1024 + tid + i * 256];
        mx = fmaxf(mx, v[i]);
    }
    red[tid] = mx; __syncthreads();
    for (int s = 128; s > 0; s >>= 1) {
        if (tid < s) red[tid] = fmaxf(red[tid], red[tid + s]);
        __syncthreads();
    }
    mx = red[0]; __syncthreads();
    float sum = 0.f;
#pragma unroll
    for (int i = 0; i < 4; i++) { v[i] = __expf(v[i] - mx); sum += v[i]; }
    red[tid] = sum; __syncthreads();
    for (int s = 128; s > 0; s >>= 1) {
        if (tid < s) red[tid] += red[tid + s];
        __syncthreads();
    }
    const float inv = 1.0f / red[0];
#pragma unroll
    for (int i = 0; i < 4; i++)
        alpha[b * 1024 + tid + i * 256] = v[i] * inv;
}

// ---------------- context = alpha^T @ features (fp32, float4) ---------------
// grid (4, 64): x = 256-wide e-chunk, y = b. 1024 threads = 64 e4-lanes x 16
// L-groups of 64. float4 global loads, LDS tree reduce.
__global__ __launch_bounds__(1024) void context_kernel(
    const float* __restrict__ alpha, const float* __restrict__ feat,
    float* __restrict__ ctx) {
    const int b  = blockIdx.y;
    const int el = threadIdx.x & 63;               // e4 lane
    const int lg = threadIdx.x >> 6;               // 0..15
    const int e  = blockIdx.x * 256 + el * 4;
    const float* fb = feat + (size_t)b * 1024 * 1024;
    const float* ab = alpha + b * 1024;
    floatx4 acc = {};
    const int l0 = lg * 64;
#pragma unroll 4
    for (int l = l0; l < l0 + 64; l++) {
        const float a = ab[l];
        const floatx4 f = *(const floatx4*)(fb + (size_t)l * 1024 + e);
        acc += a * f;
    }
    __shared__ floatx4 red[16 * 64];
    red[lg * 64 + el] = acc;
    __syncthreads();
#pragma unroll
    for (int s = 8; s > 0; s >>= 1) {
        if (lg < s) red[lg * 64 + el] += red[(lg + s) * 64 + el];
        __syncthreads();
    }
    if (lg == 0)
        *(floatx4*)(ctx + b * 1024 + e) = red[el];
}

// ---------------- fallback GEMM (fp32 A staging, padded LDS) ----------------
#define KP 72
__global__ __launch_bounds__(256) void gemm_scores_f32_kernel(
    const float* __restrict__ feat, const ushort_t* __restrict__ w1t,
    const float* __restrict__ ph, const float* __restrict__ vw,
    float* __restrict__ scores) {
    __shared__ ushort_t As[128 * KP];
    __shared__ ushort_t Bs[128 * KP];
    __shared__ float cbias[128];
    __shared__ float vvw[128];
    const int tid = threadIdx.x;
    const int n0 = blockIdx.x * 128, m0 = blockIdx.y * 128;
    const int b = m0 >> 10;
    if (tid < 128) { cbias[tid] = ph[(b << 10) + n0 + tid]; vvw[tid] = vw[n0 + tid]; }
    const int wave = tid >> 6, lane = tid & 63;
    const int wr = (wave >> 1) * 64, wc = (wave & 1) * 64;
    const int q = lane >> 4, l15 = lane & 15;
    floatx4 acc[4][4] = {};
    const int arow = tid >> 4, acol = (tid & 15) * 4;
    const int brow = tid >> 3, bcol = (tid & 7) * 8;
    const float* aptr = feat + (size_t)m0 * 1024;
    const ushort_t* bptr = w1t + (size_t)n0 * 1024;
    for (int kt = 0; kt < 1024; kt += 64) {
#pragma unroll
        for (int p = 0; p < 8; p++) {
            int r = p * 16 + arow;
            const float4 f = *(const float4*)(aptr + (size_t)r * 1024 + kt + acol);
            *(u64*)&As[r * KP + acol] = pack4(f);
        }
#pragma unroll
        for (int p = 0; p < 4; p++) {
            int r = p * 32 + brow;
            *(uint4*)&Bs[r * KP + bcol] =
                *(const uint4*)(bptr + (size_t)r * 1024 + kt + bcol);
        }
        __syncthreads();
#pragma unroll
        for (int ks = 0; ks < 64; ks += 32) {
            bf16x8 af[4], bfr[4];
#pragma unroll
            for (int t = 0; t < 4; t++)
                af[t] = *(const bf16x8*)&As[(wr + t * 16 + l15) * KP + ks + q * 8];
#pragma unroll
            for (int t = 0; t < 4; t++)
                bfr[t] = *(const bf16x8*)&Bs[(wc + t * 16 + l15) * KP + ks + q * 8];
#pragma unroll
            for (int tm = 0; tm < 4; tm++)
#pragma unroll
                for (int tn = 0; tn < 4; tn++)
                    acc[tm][tn] = __builtin_amdgcn_mfma_f32_16x16x32_bf16(
                        af[tm], bfr[tn], acc[tm][tn], 0, 0, 0);
        }
        __syncthreads();
    }
#pragma unroll
    for (int tm = 0; tm < 4; tm++) {
#pragma unroll
        for (int r = 0; r < 4; r++) {
            const int row = wr + tm * 16 + q * 4 + r;
            float s = 0.f;
#pragma unroll
            for (int tn = 0; tn < 4; tn++) {
                const int col = wc + tn * 16 + l15;
                s += tanhf(acc[tm][tn][r] + cbias[col]) * vvw[col];
            }
            s += __shfl_xor(s, 1);
            s += __shfl_xor(s, 2);
            s += __shfl_xor(s, 4);
            s += __shfl_xor(s, 8);
            if (l15 == 0) atomicAdd(&scores[m0 + row], s);
        }
    }
}

// ---------------- launcher --------------------------------------------------
extern "C" void kernel_launch(void* const* d_in, const int* in_sizes, int n_in,
                              void* d_out, int out_size, void* d_ws, size_t ws_size,
                              hipStream_t stream) {
    const float* feat = (const float*)d_in[0];   // [64,1024,1024]
    const float* hid  = (const float*)d_in[1];   // [64,1024]
    const float* w1w  = (const float*)d_in[2];   // [1024,1024]
    const float* w1b  = (const float*)d_in[3];   // [1024]
    const float* w2w  = (const float*)d_in[4];   // [1024,1024]
    const float* w2b  = (const float*)d_in[5];   // [1024]
    const float* vw   = (const float*)d_in[6];   // [1024]
    // d_in[7] = V_b: cancels in softmax -> unused

    const size_t FEATB_BYTES = (size_t)64 * 1024 * 1024 * 2;  // 128 MB
    const size_t W1T_BYTES   = (size_t)1024 * 1024 * 2;       // 2 MB
    const size_t PH_BYTES    = (size_t)64 * 1024 * 4;         // 256 KB
    const size_t SC_BYTES    = (size_t)64 * 1024 * 4;         // 256 KB
    const bool   big_ws = ws_size >= FEATB_BYTES + W1T_BYTES + PH_BYTES + SC_BYTES;
    if (!big_ws && ws_size < W1T_BYTES + PH_BYTES + SC_BYTES) return;

    char* ws = (char*)d_ws;
    ushort_t* featb = (ushort_t*)ws;
    size_t off = big_ws ? FEATB_BYTES : 0;
    ushort_t* w1t  = (ushort_t*)(ws + off);
    float* ph      = (float*)(ws + off + W1T_BYTES);
    float* scores  = (float*)(ws + off + W1T_BYTES + PH_BYTES);

    float* alpha = (float*)d_out;           // [64,1024]
    float* ctx   = alpha + 64 * 1024;       // [64,1024]

    hipMemsetAsync(scores, 0, SC_BYTES, stream);
    transpose_w1_kernel<<<dim3(16, 16), 256, 0, stream>>>(w1w, w1t);
    projh_kernel<<<dim3(16, 64), 256, 0, stream>>>(hid, w2w, w2b, w1b, ph);
    if (big_ws) {
        convert_feat_kernel<<<32768, 256, 0, stream>>>(feat, featb);
        gemm_scores_bf16_kernel<<<dim3(8, 512), 256, 0, stream>>>(
            featb, w1t, ph, vw, scores);
    } else {
        gemm_scores_f32_kernel<<<dim3(8, 512), 256, 0, stream>>>(
            feat, w1t, ph, vw, scores);
    }
    softmax_kernel<<<64, 256, 0, stream>>>(scores, alpha);
    context_kernel<<<dim3(4, 64), 1024, 0, stream>>>(alpha, feat, ctx);
}

// Round 4
// 677.625 us; speedup vs baseline: 1.1839x; 1.0592x over previous
//
#include <hip/hip_runtime.h>
#include <hip/hip_bf16.h>

// Problem: B=64, L=1024, ENC=1024, DEC=1024, ATT=1024
// M = B*L = 65536, K = ENC = 1024, N = ATT = 1024
//
// Pipeline (fast path, needs ~137 MB ws):
//   ws: [featb bf16 128MB][W1T bf16 2MB][proj_h fp32 256KB][scores fp32 256KB]
//   1. memset scores = 0
//   2. convert features fp32 -> bf16 (featb)
//   3. transpose W1 (fp32 [K][N]) -> W1T (bf16 [N][K])
//   4. proj_h = hidden@W2 + W2_b + W1_b   (combined bias)
//   5. GEMM proj_f = featb@W1T (bf16 MFMA, global_load_lds staging,
//      XOR-swizzled LDS, fast-tanh epilogue):
//        scores[m] += sum_a tanh(proj_f + proj_h[b][a]) * V_w[a]  (atomic)
//   6. softmax over L -> alpha (d_out[0:65536])   (V_b cancels in softmax)
//   7. context[b][e] = sum_l alpha*feat (fp32 feat for accuracy, float4 loads)

typedef __bf16 bf16x8 __attribute__((ext_vector_type(8)));
typedef float floatx4 __attribute__((ext_vector_type(4)));
typedef unsigned short ushort_t;
typedef unsigned long long u64;

__device__ __forceinline__ ushort_t f2b(float x) {
    union { float f; unsigned u; } v; v.f = x;
    unsigned r = (v.u + 0x7fffu + ((v.u >> 16) & 1u)) >> 16;  // RNE
    return (ushort_t)r;
}

__device__ __forceinline__ u64 pack4(float4 f) {
    return (u64)f2b(f.x) | ((u64)f2b(f.y) << 16) |
           ((u64)f2b(f.z) << 32) | ((u64)f2b(f.w) << 48);
}

__device__ __forceinline__ void gload_lds16(const void* g, void* l) {
    __builtin_amdgcn_global_load_lds(
        (const __attribute__((address_space(1))) void*)g,
        (__attribute__((address_space(3))) void*)l, 16, 0, 0);
}

// tanh via v_exp_f32 + v_rcp_f32: ~7 VALU ops, branch-free, ~1e-6 abs error.
// tanhf (OCML libcall) was ~40% of the GEMM kernel's VALU time.
__device__ __forceinline__ float fast_tanh(float x) {
    const float ax = fabsf(x);
    const float t  = __expf(-2.0f * ax);          // e^{-2|x|}, v_exp_f32
    const float r  = (1.0f - t) * __builtin_amdgcn_rcpf(1.0f + t);
    return copysignf(r, x);                       // v_bfi
}

// ---------------- features fp32 -> bf16 -------------------------------------
__global__ __launch_bounds__(256) void convert_feat_kernel(
    const float* __restrict__ feat, ushort_t* __restrict__ featb) {
    const size_t idx = ((size_t)blockIdx.x * 256 + threadIdx.x) * 8;
    const float4 f0 = *(const float4*)(feat + idx);
    const float4 f1 = *(const float4*)(feat + idx + 4);
    *(u64*)(featb + idx)     = pack4(f0);
    *(u64*)(featb + idx + 4) = pack4(f1);
}

// ---------------- W1 transpose + bf16 convert: [K][N] fp32 -> [N][K] bf16 ---
__global__ __launch_bounds__(256) void transpose_w1_kernel(
    const float* __restrict__ w1, ushort_t* __restrict__ w1t) {
    __shared__ ushort_t tile[64][65];
    const int k0 = blockIdx.x * 64, n0 = blockIdx.y * 64;
    const int tr = threadIdx.x >> 6;   // 0..3
    const int tc = threadIdx.x & 63;   // 0..63
#pragma unroll
    for (int i = 0; i < 16; i++) {
        int r = i * 4 + tr;
        tile[tc][r] = f2b(w1[(size_t)(k0 + r) * 1024 + n0 + tc]);
    }
    __syncthreads();
#pragma unroll
    for (int i = 0; i < 16; i++) {
        int r = i * 4 + tr;
        w1t[(size_t)(n0 + r) * 1024 + k0 + tc] = tile[r][tc];
    }
}

// ---------------- proj_h = hidden @ W2 + W2_b + W1_b ------------------------
// grid (16, 64): x = 64-wide a-chunk, y = b. 256 thr = 64 a x 4 e-groups.
__global__ __launch_bounds__(256) void projh_kernel(
    const float* __restrict__ hidden, const float* __restrict__ w2,
    const float* __restrict__ w2b, const float* __restrict__ w1b,
    float* __restrict__ ph) {
    const int b  = blockIdx.y;
    const int al = threadIdx.x & 63;
    const int eg = threadIdx.x >> 6;            // 0..3
    const int a  = blockIdx.x * 64 + al;
    const float* h = hidden + b * 1024;
    float sum = 0.f;
    const int e0 = eg * 256;
#pragma unroll 8
    for (int e = e0; e < e0 + 256; e++)
        sum += h[e] * w2[(size_t)e * 1024 + a];
    __shared__ float red[256];
    red[threadIdx.x] = sum;
    __syncthreads();
    if (threadIdx.x < 64)
        ph[b * 1024 + a] = w2b[a] + w1b[a] + red[al] + red[al + 64] +
                           red[al + 128] + red[al + 192];
}

// ---------------- main GEMM (m97 structure + XOR swizzle) -------------------
// tile 128x128, BK=64, 256 threads (4 waves, each 64x64 = 4x4 MFMA tiles)
// LDS rows are 8 x 16B blocks; block b of row r holds global block b^(r&7).
__global__ __launch_bounds__(256) void gemm_scores_bf16_kernel(
    const ushort_t* __restrict__ featb,  // [M][1024] bf16
    const ushort_t* __restrict__ w1t,    // [N][1024] bf16
    const float* __restrict__ ph,        // [B][1024] combined bias
    const float* __restrict__ vw,        // [1024]
    float* __restrict__ scores) {        // [M] fp32, pre-zeroed, atomic
    __shared__ ushort_t As[128 * 64];
    __shared__ ushort_t Bs[128 * 64];
    __shared__ float cbias[128];
    __shared__ float vvw[128];

    const int tid = threadIdx.x;
    const int n0 = blockIdx.x * 128;
    const int m0 = blockIdx.y * 128;
    const int b  = m0 >> 10;             // L=1024, BM=128 -> one b per block

    if (tid < 128) {
        cbias[tid] = ph[(b << 10) + n0 + tid];
        vvw[tid]   = vw[n0 + tid];
    }

    const int wave = tid >> 6;
    const int lane = tid & 63;
    const int wr = (wave >> 1) * 64;
    const int wc = (wave & 1) * 64;
    const int q  = lane >> 4;
    const int l15 = lane & 15;

    floatx4 acc[4][4] = {};

    // staging: lane i -> LDS row seg*8+(i>>3), LDS block i&7;
    // global block loaded = (i&7)^(i>>3)  => LDS blk b holds glob blk b^(r&7)
    const int srow = lane >> 3;                          // 0..7
    const int scol = ((lane & 7) ^ srow) << 3;           // swizzled, x8 ushorts

    const ushort_t* aBase = featb + (size_t)m0 * 1024;
    const ushort_t* bBase = w1t  + (size_t)n0 * 1024;

    for (int kt = 0; kt < 1024; kt += 64) {
#pragma unroll
        for (int p = 0; p < 4; p++) {
            const int seg = wave * 4 + p;            // 0..15
            const int row = seg * 8 + srow;
            gload_lds16(aBase + (size_t)row * 1024 + kt + scol, As + seg * 512);
            gload_lds16(bBase + (size_t)row * 1024 + kt + scol, Bs + seg * 512);
        }
        __syncthreads();
#pragma unroll
        for (int ks = 0; ks < 64; ks += 32) {
            bf16x8 af[4], bfr[4];
#pragma unroll
            for (int t = 0; t < 4; t++) {
                const int r = wr + t * 16 + l15;
                const int g = (ks >> 3) + q;         // global 16B-block 0..7
                af[t] = *(const bf16x8*)&As[r * 64 + ((g ^ (r & 7)) << 3)];
            }
#pragma unroll
            for (int t = 0; t < 4; t++) {
                const int r = wc + t * 16 + l15;
                const int g = (ks >> 3) + q;
                bfr[t] = *(const bf16x8*)&Bs[r * 64 + ((g ^ (r & 7)) << 3)];
            }
#pragma unroll
            for (int tm = 0; tm < 4; tm++)
#pragma unroll
                for (int tn = 0; tn < 4; tn++)
                    acc[tm][tn] = __builtin_amdgcn_mfma_f32_16x16x32_bf16(
                        af[tm], bfr[tn], acc[tm][tn], 0, 0, 0);
        }
        __syncthreads();
    }

    // Epilogue: C/D layout col=lane&15, row=quad*4+reg (measured m89/m91).
#pragma unroll
    for (int tm = 0; tm < 4; tm++) {
#pragma unroll
        for (int r = 0; r < 4; r++) {
            const int row = wr + tm * 16 + q * 4 + r;
            float s = 0.f;
#pragma unroll
            for (int tn = 0; tn < 4; tn++) {
                const int col = wc + tn * 16 + l15;
                s += fast_tanh(acc[tm][tn][r] + cbias[col]) * vvw[col];
            }
            s += __shfl_xor(s, 1);
            s += __shfl_xor(s, 2);
            s += __shfl_xor(s, 4);
            s += __shfl_xor(s, 8);
            if (l15 == 0) atomicAdd(&scores[m0 + row], s);
        }
    }
}

// ---------------- softmax over L per b --------------------------------------
__global__ __launch_bounds__(256) void softmax_kernel(
    const float* __restrict__ scores, float* __restrict__ alpha) {
    const int b = blockIdx.x;
    const int tid = threadIdx.x;
    __shared__ float red[256];
    float v[4];
    float mx = -1e30f;
#pragma unroll
    for (int i = 0; i < 4; i++) {
        v[i] = scores[b * 1024 + tid + i * 256];
        mx = fmaxf(mx, v[i]);
    }
    red[tid] = mx; __syncthreads();
    for (int s = 128; s > 0; s >>= 1) {
        if (tid < s) red[tid] = fmaxf(red[tid], red[tid + s]);
        __syncthreads();
    }
    mx = red[0]; __syncthreads();
    float sum = 0.f;
#pragma unroll
    for (int i = 0; i < 4; i++) { v[i] = __expf(v[i] - mx); sum += v[i]; }
    red[tid] = sum; __syncthreads();
    for (int s = 128; s > 0; s >>= 1) {
        if (tid < s) red[tid] += red[tid + s];
        __syncthreads();
    }
    const float inv = 1.0f / red[0];
#pragma unroll
    for (int i = 0; i < 4; i++)
        alpha[b * 1024 + tid + i * 256] = v[i] * inv;
}

// ---------------- context = alpha^T @ features (fp32, float4) ---------------
// grid (4, 64): x = 256-wide e-chunk, y = b. 1024 threads = 64 e4-lanes x 16
// L-groups of 64. float4 global loads, LDS tree reduce.
__global__ __launch_bounds__(1024) void context_kernel(
    const float* __restrict__ alpha, const float* __restrict__ feat,
    float* __restrict__ ctx) {
    const int b  = blockIdx.y;
    const int el = threadIdx.x & 63;               // e4 lane
    const int lg = threadIdx.x >> 6;               // 0..15
    const int e  = blockIdx.x * 256 + el * 4;
    const float* fb = feat + (size_t)b * 1024 * 1024;
    const float* ab = alpha + b * 1024;
    floatx4 acc = {};
    const int l0 = lg * 64;
#pragma unroll 4
    for (int l = l0; l < l0 + 64; l++) {
        const float a = ab[l];
        const floatx4 f = *(const floatx4*)(fb + (size_t)l * 1024 + e);
        acc += a * f;
    }
    __shared__ floatx4 red[16 * 64];
    red[lg * 64 + el] = acc;
    __syncthreads();
#pragma unroll
    for (int s = 8; s > 0; s >>= 1) {
        if (lg < s) red[lg * 64 + el] += red[(lg + s) * 64 + el];
        __syncthreads();
    }
    if (lg == 0)
        *(floatx4*)(ctx + b * 1024 + e) = red[el];
}

// ---------------- fallback GEMM (fp32 A staging, padded LDS) ----------------
#define KP 72
__global__ __launch_bounds__(256) void gemm_scores_f32_kernel(
    const float* __restrict__ feat, const ushort_t* __restrict__ w1t,
    const float* __restrict__ ph, const float* __restrict__ vw,
    float* __restrict__ scores) {
    __shared__ ushort_t As[128 * KP];
    __shared__ ushort_t Bs[128 * KP];
    __shared__ float cbias[128];
    __shared__ float vvw[128];
    const int tid = threadIdx.x;
    const int n0 = blockIdx.x * 128, m0 = blockIdx.y * 128;
    const int b = m0 >> 10;
    if (tid < 128) { cbias[tid] = ph[(b << 10) + n0 + tid]; vvw[tid] = vw[n0 + tid]; }
    const int wave = tid >> 6, lane = tid & 63;
    const int wr = (wave >> 1) * 64, wc = (wave & 1) * 64;
    const int q = lane >> 4, l15 = lane & 15;
    floatx4 acc[4][4] = {};
    const int arow = tid >> 4, acol = (tid & 15) * 4;
    const int brow = tid >> 3, bcol = (tid & 7) * 8;
    const float* aptr = feat + (size_t)m0 * 1024;
    const ushort_t* bptr = w1t + (size_t)n0 * 1024;
    for (int kt = 0; kt < 1024; kt += 64) {
#pragma unroll
        for (int p = 0; p < 8; p++) {
            int r = p * 16 + arow;
            const float4 f = *(const float4*)(aptr + (size_t)r * 1024 + kt + acol);
            *(u64*)&As[r * KP + acol] = pack4(f);
        }
#pragma unroll
        for (int p = 0; p < 4; p++) {
            int r = p * 32 + brow;
            *(uint4*)&Bs[r * KP + bcol] =
                *(const uint4*)(bptr + (size_t)r * 1024 + kt + bcol);
        }
        __syncthreads();
#pragma unroll
        for (int ks = 0; ks < 64; ks += 32) {
            bf16x8 af[4], bfr[4];
#pragma unroll
            for (int t = 0; t < 4; t++)
                af[t] = *(const bf16x8*)&As[(wr + t * 16 + l15) * KP + ks + q * 8];
#pragma unroll
            for (int t = 0; t < 4; t++)
                bfr[t] = *(const bf16x8*)&Bs[(wc + t * 16 + l15) * KP + ks + q * 8];
#pragma unroll
            for (int tm = 0; tm < 4; tm++)
#pragma unroll
                for (int tn = 0; tn < 4; tn++)
                    acc[tm][tn] = __builtin_amdgcn_mfma_f32_16x16x32_bf16(
                        af[tm], bfr[tn], acc[tm][tn], 0, 0, 0);
        }
        __syncthreads();
    }
#pragma unroll
    for (int tm = 0; tm < 4; tm++) {
#pragma unroll
        for (int r = 0; r < 4; r++) {
            const int row = wr + tm * 16 + q * 4 + r;
            float s = 0.f;
#pragma unroll
            for (int tn = 0; tn < 4; tn++) {
                const int col = wc + tn * 16 + l15;
                s += fast_tanh(acc[tm][tn][r] + cbias[col]) * vvw[col];
            }
            s += __shfl_xor(s, 1);
            s += __shfl_xor(s, 2);
            s += __shfl_xor(s, 4);
            s += __shfl_xor(s, 8);
            if (l15 == 0) atomicAdd(&scores[m0 + row], s);
        }
    }
}

// ---------------- launcher --------------------------------------------------
extern "C" void kernel_launch(void* const* d_in, const int* in_sizes, int n_in,
                              void* d_out, int out_size, void* d_ws, size_t ws_size,
                              hipStream_t stream) {
    const float* feat = (const float*)d_in[0];   // [64,1024,1024]
    const float* hid  = (const float*)d_in[1];   // [64,1024]
    const float* w1w  = (const float*)d_in[2];   // [1024,1024]
    const float* w1b  = (const float*)d_in[3];   // [1024]
    const float* w2w  = (const float*)d_in[4];   // [1024,1024]
    const float* w2b  = (const float*)d_in[5];   // [1024]
    const float* vw   = (const float*)d_in[6];   // [1024]
    // d_in[7] = V_b: cancels in softmax -> unused

    const size_t FEATB_BYTES = (size_t)64 * 1024 * 1024 * 2;  // 128 MB
    const size_t W1T_BYTES   = (size_t)1024 * 1024 * 2;       // 2 MB
    const size_t PH_BYTES    = (size_t)64 * 1024 * 4;         // 256 KB
    const size_t SC_BYTES    = (size_t)64 * 1024 * 4;         // 256 KB
    const bool   big_ws = ws_size >= FEATB_BYTES + W1T_BYTES + PH_BYTES + SC_BYTES;
    if (!big_ws && ws_size < W1T_BYTES + PH_BYTES + SC_BYTES) return;

    char* ws = (char*)d_ws;
    ushort_t* featb = (ushort_t*)ws;
    size_t off = big_ws ? FEATB_BYTES : 0;
    ushort_t* w1t  = (ushort_t*)(ws + off);
    float* ph      = (float*)(ws + off + W1T_BYTES);
    float* scores  = (float*)(ws + off + W1T_BYTES + PH_BYTES);

    float* alpha = (float*)d_out;           // [64,1024]
    float* ctx   = alpha + 64 * 1024;       // [64,1024]

    hipMemsetAsync(scores, 0, SC_BYTES, stream);
    transpose_w1_kernel<<<dim3(16, 16), 256, 0, stream>>>(w1w, w1t);
    projh_kernel<<<dim3(16, 64), 256, 0, stream>>>(hid, w2w, w2b, w1b, ph);
    if (big_ws) {
        convert_feat_kernel<<<32768, 256, 0, stream>>>(feat, featb);
        gemm_scores_bf16_kernel<<<dim3(8, 512), 256, 0, stream>>>(
            featb, w1t, ph, vw, scores);
    } else {
        gemm_scores_f32_kernel<<<dim3(8, 512), 256, 0, stream>>>(
            feat, w1t, ph, vw, scores);
    }
    softmax_kernel<<<64, 256, 0, stream>>>(scores, alpha);
    context_kernel<<<dim3(4, 64), 1024, 0, stream>>>(alpha, feat, ctx);
}

// Round 6
// 672.394 us; speedup vs baseline: 1.1931x; 1.0078x over previous
//
#include <hip/hip_runtime.h>
#include <hip/hip_bf16.h>

// Problem: B=64, L=1024, ENC=1024, DEC=1024, ATT=1024
// M = B*L = 65536, K = ENC = 1024, N = ATT = 1024
//
// Pipeline (fast path, needs ~135 MB ws):
//   ws: [featb bf16 128MB][W1T bf16 2MB][proj_h fp32 256KB][part fp32 4MB]
//   1. convert features fp32 -> bf16 (featb)
//   2. transpose W1 (fp32 [K][N]) -> W1T (bf16 [N][K])
//   3. proj_h = hidden@W2 + W2_b + W1_b   (combined bias)
//   4. GEMM proj_f = featb@W1T (bf16 MFMA, global_load_lds staging,
//      XOR-swizzled LDS, fast-tanh epilogue, XCD-aware block remap):
//        part[nt*2 + colhalf][m] = sum_{a in 64-col chunk} tanh(pf+ph)*V_w
//      (16 slices: two waves share each row with different column halves --
//       direct non-atomic stores require separate slots per wave. R5 bug.)
//   5. softmax over L (summing 16 partials/row) -> alpha (d_out[0:65536])
//   6. context[b][e] = sum_l alpha*feat (fp32 feat for accuracy, float4 loads)

typedef __bf16 bf16x8 __attribute__((ext_vector_type(8)));
typedef float floatx4 __attribute__((ext_vector_type(4)));
typedef unsigned short ushort_t;
typedef unsigned long long u64;

__device__ __forceinline__ ushort_t f2b(float x) {
    union { float f; unsigned u; } v; v.f = x;
    unsigned r = (v.u + 0x7fffu + ((v.u >> 16) & 1u)) >> 16;  // RNE
    return (ushort_t)r;
}

__device__ __forceinline__ u64 pack4(float4 f) {
    return (u64)f2b(f.x) | ((u64)f2b(f.y) << 16) |
           ((u64)f2b(f.z) << 32) | ((u64)f2b(f.w) << 48);
}

__device__ __forceinline__ void gload_lds16(const void* g, void* l) {
    __builtin_amdgcn_global_load_lds(
        (const __attribute__((address_space(1))) void*)g,
        (__attribute__((address_space(3))) void*)l, 16, 0, 0);
}

// tanh via v_exp_f32 + v_rcp_f32: ~7 VALU ops, branch-free, ~1e-6 abs error.
__device__ __forceinline__ float fast_tanh(float x) {
    const float ax = fabsf(x);
    const float t  = __expf(-2.0f * ax);          // e^{-2|x|}, v_exp_f32
    const float r  = (1.0f - t) * __builtin_amdgcn_rcpf(1.0f + t);
    return copysignf(r, x);                       // v_bfi
}

// ---------------- features fp32 -> bf16 -------------------------------------
__global__ __launch_bounds__(256) void convert_feat_kernel(
    const float* __restrict__ feat, ushort_t* __restrict__ featb) {
    const size_t idx = ((size_t)blockIdx.x * 256 + threadIdx.x) * 8;
    const float4 f0 = *(const float4*)(feat + idx);
    const float4 f1 = *(const float4*)(feat + idx + 4);
    *(u64*)(featb + idx)     = pack4(f0);
    *(u64*)(featb + idx + 4) = pack4(f1);
}

// ---------------- W1 transpose + bf16 convert: [K][N] fp32 -> [N][K] bf16 ---
__global__ __launch_bounds__(256) void transpose_w1_kernel(
    const float* __restrict__ w1, ushort_t* __restrict__ w1t) {
    __shared__ ushort_t tile[64][65];
    const int k0 = blockIdx.x * 64, n0 = blockIdx.y * 64;
    const int tr = threadIdx.x >> 6;   // 0..3
    const int tc = threadIdx.x & 63;   // 0..63
#pragma unroll
    for (int i = 0; i < 16; i++) {
        int r = i * 4 + tr;
        tile[tc][r] = f2b(w1[(size_t)(k0 + r) * 1024 + n0 + tc]);
    }
    __syncthreads();
#pragma unroll
    for (int i = 0; i < 16; i++) {
        int r = i * 4 + tr;
        w1t[(size_t)(n0 + r) * 1024 + k0 + tc] = tile[r][tc];
    }
}

// ---------------- proj_h = hidden @ W2 + W2_b + W1_b ------------------------
__global__ __launch_bounds__(256) void projh_kernel(
    const float* __restrict__ hidden, const float* __restrict__ w2,
    const float* __restrict__ w2b, const float* __restrict__ w1b,
    float* __restrict__ ph) {
    const int b  = blockIdx.y;
    const int al = threadIdx.x & 63;
    const int eg = threadIdx.x >> 6;            // 0..3
    const int a  = blockIdx.x * 64 + al;
    const float* h = hidden + b * 1024;
    float sum = 0.f;
    const int e0 = eg * 256;
#pragma unroll 8
    for (int e = e0; e < e0 + 256; e++)
        sum += h[e] * w2[(size_t)e * 1024 + a];
    __shared__ float red[256];
    red[threadIdx.x] = sum;
    __syncthreads();
    if (threadIdx.x < 64)
        ph[b * 1024 + a] = w2b[a] + w1b[a] + red[al] + red[al + 64] +
                           red[al + 128] + red[al + 192];
}

// ---------------- main GEMM (m97 structure + XOR swizzle + XCD remap) -------
// tile 128x128, BK=64, 256 threads (4 waves, each 64x64 = 4x4 MFMA tiles)
// Block remap: lid = 64q + 8j + c -> m-tile = q*8+c, n-tile = j. The 8 blocks
// sharing one A-tile are temporally adjacent AND in the same mod-8 lid class
// (same XCD under round-robin or chunked assignment) -> A fetched ~once/L2.
__global__ __launch_bounds__(256) void gemm_scores_bf16_kernel(
    const ushort_t* __restrict__ featb,  // [M][1024] bf16
    const ushort_t* __restrict__ w1t,    // [N][1024] bf16
    const float* __restrict__ ph,        // [B][1024] combined bias
    const float* __restrict__ vw,        // [1024]
    float* __restrict__ part) {          // [16][M] fp32 partial scores
    __shared__ ushort_t As[128 * 64];
    __shared__ ushort_t Bs[128 * 64];
    __shared__ float cbias[128];
    __shared__ float vvw[128];

    const int tid = threadIdx.x;
    const int lid = blockIdx.y * 8 + blockIdx.x;     // HW linear id, x fastest
    const int c   = lid & 7;
    const int rr  = lid >> 3;
    const int mt  = (rr >> 3) * 8 + c;               // m-tile 0..511
    const int nt  = rr & 7;                          // n-tile 0..7
    const int n0 = nt * 128;
    const int m0 = mt * 128;
    const int b  = m0 >> 10;             // L=1024, BM=128 -> one b per block

    if (tid < 128) {
        cbias[tid] = ph[(b << 10) + n0 + tid];
        vvw[tid]   = vw[n0 + tid];
    }

    const int wave = tid >> 6;
    const int lane = tid & 63;
    const int wr = (wave >> 1) * 64;
    const int wc = (wave & 1) * 64;
    const int q  = lane >> 4;
    const int l15 = lane & 15;

    floatx4 acc[4][4] = {};

    // staging: lane i -> LDS row seg*8+(i>>3), LDS block i&7;
    // global block loaded = (i&7)^(i>>3)  => LDS blk b holds glob blk b^(r&7)
    const int srow = lane >> 3;                          // 0..7
    const int scol = ((lane & 7) ^ srow) << 3;           // swizzled, x8 ushorts

    const ushort_t* aBase = featb + (size_t)m0 * 1024;
    const ushort_t* bBase = w1t  + (size_t)n0 * 1024;

    for (int kt = 0; kt < 1024; kt += 64) {
#pragma unroll
        for (int p = 0; p < 4; p++) {
            const int seg = wave * 4 + p;            // 0..15
            const int row = seg * 8 + srow;
            gload_lds16(aBase + (size_t)row * 1024 + kt + scol, As + seg * 512);
            gload_lds16(bBase + (size_t)row * 1024 + kt + scol, Bs + seg * 512);
        }
        __syncthreads();
#pragma unroll
        for (int ks = 0; ks < 64; ks += 32) {
            bf16x8 af[4], bfr[4];
#pragma unroll
            for (int t = 0; t < 4; t++) {
                const int r = wr + t * 16 + l15;
                const int g = (ks >> 3) + q;         // global 16B-block 0..7
                af[t] = *(const bf16x8*)&As[r * 64 + ((g ^ (r & 7)) << 3)];
            }
#pragma unroll
            for (int t = 0; t < 4; t++) {
                const int r = wc + t * 16 + l15;
                const int g = (ks >> 3) + q;
                bfr[t] = *(const bf16x8*)&Bs[r * 64 + ((g ^ (r & 7)) << 3)];
            }
#pragma unroll
            for (int tm = 0; tm < 4; tm++)
#pragma unroll
                for (int tn = 0; tn < 4; tn++)
                    acc[tm][tn] = __builtin_amdgcn_mfma_f32_16x16x32_bf16(
                        af[tm], bfr[tn], acc[tm][tn], 0, 0, 0);
        }
        __syncthreads();
    }

    // Epilogue: C/D layout col=lane&15, row=quad*4+reg (measured m89/m91).
    // Waves 0/1 (and 2/3) share rows but cover different column halves ->
    // each wave-column-half gets its own partial slice (R5 race fix).
    const int slot = nt * 2 + (wave & 1);
#pragma unroll
    for (int tm = 0; tm < 4; tm++) {
#pragma unroll
        for (int r = 0; r < 4; r++) {
            const int row = wr + tm * 16 + q * 4 + r;
            float s = 0.f;
#pragma unroll
            for (int tn = 0; tn < 4; tn++) {
                const int col = wc + tn * 16 + l15;
                s += fast_tanh(acc[tm][tn][r] + cbias[col]) * vvw[col];
            }
            s += __shfl_xor(s, 1);
            s += __shfl_xor(s, 2);
            s += __shfl_xor(s, 4);
            s += __shfl_xor(s, 8);
            if (l15 == 0) part[slot * 65536 + m0 + row] = s;
        }
    }
}

// ---------------- softmax over L per b (sums 16 partials/row) ---------------
__global__ __launch_bounds__(256) void softmax_kernel(
    const float* __restrict__ part, float* __restrict__ alpha) {
    const int b = blockIdx.x;
    const int tid = threadIdx.x;
    __shared__ float red[256];
    float v[4];
    float mx = -1e30f;
#pragma unroll
    for (int i = 0; i < 4; i++) {
        const int m = b * 1024 + tid + i * 256;
        float s = 0.f;
#pragma unroll
        for (int nb = 0; nb < 16; nb++) s += part[nb * 65536 + m];
        v[i] = s;
        mx = fmaxf(mx, s);
    }
    red[tid] = mx; __syncthreads();
    for (int s = 128; s > 0; s >>= 1) {
        if (tid < s) red[tid] = fmaxf(red[tid], red[tid + s]);
        __syncthreads();
    }
    mx = red[0]; __syncthreads();
    float sum = 0.f;
#pragma unroll
    for (int i = 0; i < 4; i++) { v[i] = __expf(v[i] - mx); sum += v[i]; }
    red[tid] = sum; __syncthreads();
    for (int s = 128; s > 0; s >>= 1) {
        if (tid < s) red[tid] += red[tid + s];
        __syncthreads();
    }
    const float inv = 1.0f / red[0];
#pragma unroll
    for (int i = 0; i < 4; i++)
        alpha[b * 1024 + tid + i * 256] = v[i] * inv;
}

// ---------------- context = alpha^T @ features (fp32, float4) ---------------
__global__ __launch_bounds__(1024) void context_kernel(
    const float* __restrict__ alpha, const float* __restrict__ feat,
    float* __restrict__ ctx) {
    const int b  = blockIdx.y;
    const int el = threadIdx.x & 63;               // e4 lane
    const int lg = threadIdx.x >> 6;               // 0..15
    const int e  = blockIdx.x * 256 + el * 4;
    const float* fb = feat + (size_t)b * 1024 * 1024;
    const float* ab = alpha + b * 1024;
    floatx4 acc = {};
    const int l0 = lg * 64;
#pragma unroll 4
    for (int l = l0; l < l0 + 64; l++) {
        const float a = ab[l];
        const floatx4 f = *(const floatx4*)(fb + (size_t)l * 1024 + e);
        acc += a * f;
    }
    __shared__ floatx4 red[16 * 64];
    red[lg * 64 + el] = acc;
    __syncthreads();
#pragma unroll
    for (int s = 8; s > 0; s >>= 1) {
        if (lg < s) red[lg * 64 + el] += red[(lg + s) * 64 + el];
        __syncthreads();
    }
    if (lg == 0)
        *(floatx4*)(ctx + b * 1024 + e) = red[el];
}

// ---------------- fallback GEMM (fp32 A staging, padded LDS) ----------------
#define KP 72
__global__ __launch_bounds__(256) void gemm_scores_f32_kernel(
    const float* __restrict__ feat, const ushort_t* __restrict__ w1t,
    const float* __restrict__ ph, const float* __restrict__ vw,
    float* __restrict__ part) {
    __shared__ ushort_t As[128 * KP];
    __shared__ ushort_t Bs[128 * KP];
    __shared__ float cbias[128];
    __shared__ float vvw[128];
    const int tid = threadIdx.x;
    const int nt = blockIdx.x, n0 = nt * 128, m0 = blockIdx.y * 128;
    const int b = m0 >> 10;
    if (tid < 128) { cbias[tid] = ph[(b << 10) + n0 + tid]; vvw[tid] = vw[n0 + tid]; }
    const int wave = tid >> 6, lane = tid & 63;
    const int wr = (wave >> 1) * 64, wc = (wave & 1) * 64;
    const int q = lane >> 4, l15 = lane & 15;
    floatx4 acc[4][4] = {};
    const int arow = tid >> 4, acol = (tid & 15) * 4;
    const int brow = tid >> 3, bcol = (tid & 7) * 8;
    const float* aptr = feat + (size_t)m0 * 1024;
    const ushort_t* bptr = w1t + (size_t)n0 * 1024;
    for (int kt = 0; kt < 1024; kt += 64) {
#pragma unroll
        for (int p = 0; p < 8; p++) {
            int r = p * 16 + arow;
            const float4 f = *(const float4*)(aptr + (size_t)r * 1024 + kt + acol);
            *(u64*)&As[r * KP + acol] = pack4(f);
        }
#pragma unroll
        for (int p = 0; p < 4; p++) {
            int r = p * 32 + brow;
            *(uint4*)&Bs[r * KP + bcol] =
                *(const uint4*)(bptr + (size_t)r * 1024 + kt + bcol);
        }
        __syncthreads();
#pragma unroll
        for (int ks = 0; ks < 64; ks += 32) {
            bf16x8 af[4], bfr[4];
#pragma unroll
            for (int t = 0; t < 4; t++)
                af[t] = *(const bf16x8*)&As[(wr + t * 16 + l15) * KP + ks + q * 8];
#pragma unroll
            for (int t = 0; t < 4; t++)
                bfr[t] = *(const bf16x8*)&Bs[(wc + t * 16 + l15) * KP + ks + q * 8];
#pragma unroll
            for (int tm = 0; tm < 4; tm++)
#pragma unroll
                for (int tn = 0; tn < 4; tn++)
                    acc[tm][tn] = __builtin_amdgcn_mfma_f32_16x16x32_bf16(
                        af[tm], bfr[tn], acc[tm][tn], 0, 0, 0);
        }
        __syncthreads();
    }
    const int slot = nt * 2 + (wave & 1);
#pragma unroll
    for (int tm = 0; tm < 4; tm++) {
#pragma unroll
        for (int r = 0; r < 4; r++) {
            const int row = wr + tm * 16 + q * 4 + r;
            float s = 0.f;
#pragma unroll
            for (int tn = 0; tn < 4; tn++) {
                const int col = wc + tn * 16 + l15;
                s += fast_tanh(acc[tm][tn][r] + cbias[col]) * vvw[col];
            }
            s += __shfl_xor(s, 1);
            s += __shfl_xor(s, 2);
            s += __shfl_xor(s, 4);
            s += __shfl_xor(s, 8);
            if (l15 == 0) part[slot * 65536 + m0 + row] = s;
        }
    }
}

// ---------------- launcher --------------------------------------------------
extern "C" void kernel_launch(void* const* d_in, const int* in_sizes, int n_in,
                              void* d_out, int out_size, void* d_ws, size_t ws_size,
                              hipStream_t stream) {
    const float* feat = (const float*)d_in[0];   // [64,1024,1024]
    const float* hid  = (const float*)d_in[1];   // [64,1024]
    const float* w1w  = (const float*)d_in[2];   // [1024,1024]
    const float* w1b  = (const float*)d_in[3];   // [1024]
    const float* w2w  = (const float*)d_in[4];   // [1024,1024]
    const float* w2b  = (const float*)d_in[5];   // [1024]
    const float* vw   = (const float*)d_in[6];   // [1024]
    // d_in[7] = V_b: cancels in softmax -> unused

    const size_t FEATB_BYTES = (size_t)64 * 1024 * 1024 * 2;  // 128 MB
    const size_t W1T_BYTES   = (size_t)1024 * 1024 * 2;       // 2 MB
    const size_t PH_BYTES    = (size_t)64 * 1024 * 4;         // 256 KB
    const size_t PART_BYTES  = (size_t)16 * 65536 * 4;        // 4 MB
    const bool   big_ws = ws_size >= FEATB_BYTES + W1T_BYTES + PH_BYTES + PART_BYTES;
    if (!big_ws && ws_size < W1T_BYTES + PH_BYTES + PART_BYTES) return;

    char* ws = (char*)d_ws;
    ushort_t* featb = (ushort_t*)ws;
    size_t off = big_ws ? FEATB_BYTES : 0;
    ushort_t* w1t  = (ushort_t*)(ws + off);
    float* ph      = (float*)(ws + off + W1T_BYTES);
    float* part    = (float*)(ws + off + W1T_BYTES + PH_BYTES);

    float* alpha = (float*)d_out;           // [64,1024]
    float* ctx   = alpha + 64 * 1024;       // [64,1024]

    transpose_w1_kernel<<<dim3(16, 16), 256, 0, stream>>>(w1w, w1t);
    projh_kernel<<<dim3(16, 64), 256, 0, stream>>>(hid, w2w, w2b, w1b, ph);
    if (big_ws) {
        convert_feat_kernel<<<32768, 256, 0, stream>>>(feat, featb);
        gemm_scores_bf16_kernel<<<dim3(8, 512), 256, 0, stream>>>(
            featb, w1t, ph, vw, part);
    } else {
        gemm_scores_f32_kernel<<<dim3(8, 512), 256, 0, stream>>>(
            feat, w1t, ph, vw, part);
    }
    softmax_kernel<<<64, 256, 0, stream>>>(part, alpha);
    context_kernel<<<dim3(4, 64), 1024, 0, stream>>>(alpha, feat, ctx);
}

// Round 7
// 644.254 us; speedup vs baseline: 1.2452x; 1.0437x over previous
//
#include <hip/hip_runtime.h>
#include <hip/hip_bf16.h>

// Problem: B=64, L=1024, ENC=1024, DEC=1024, ATT=1024
// M = B*L = 65536, K = ENC = 1024, N = ATT = 1024
//
// Pipeline (fast path, needs ~135 MB ws):
//   ws: [featb bf16 128MB][W1T bf16 2MB][proj_h fp32 256KB][part fp32 4MB]
//   1. convert features fp32 -> bf16 (featb)
//   2. transpose W1 (fp32 [K][N]) -> W1T (bf16 [N][K])
//   3. proj_h = hidden@W2 + W2_b + W1_b   (combined bias)
//   4. GEMM proj_f = featb@W1T (bf16 MFMA, global_load_lds staging,
//      XOR-swizzled LDS, cheap-tanh epilogue, XCD-aware block remap):
//        part[nt*2 + colhalf][m] = sum_{a in 64-col chunk} tanh(pf+ph)*V_w
//   5. softmax over L (summing 16 partials/row) -> alpha (d_out[0:65536])
//   6. context[b][e] = sum_l alpha*featb (bf16 feat: halves traffic; error
//      contribution ~5e-4 << 2.7e-3 threshold)

typedef __bf16 bf16x8 __attribute__((ext_vector_type(8)));
typedef float floatx4 __attribute__((ext_vector_type(4)));
typedef unsigned short ushort_t;
typedef unsigned long long u64;

__device__ __forceinline__ ushort_t f2b(float x) {
    union { float f; unsigned u; } v; v.f = x;
    unsigned r = (v.u + 0x7fffu + ((v.u >> 16) & 1u)) >> 16;  // RNE
    return (ushort_t)r;
}

__device__ __forceinline__ float b2f(ushort_t u) {
    union { unsigned u; float f; } v; v.u = (unsigned)u << 16; return v.f;
}

__device__ __forceinline__ u64 pack4(float4 f) {
    return (u64)f2b(f.x) | ((u64)f2b(f.y) << 16) |
           ((u64)f2b(f.z) << 32) | ((u64)f2b(f.w) << 48);
}

__device__ __forceinline__ void gload_lds16(const void* g, void* l) {
    __builtin_amdgcn_global_load_lds(
        (const __attribute__((address_space(1))) void*)g,
        (__attribute__((address_space(3))) void*)l, 16, 0, 0);
}

// tanh via v_exp_f32 + v_rcp_f32 (fallback kernel only)
__device__ __forceinline__ float fast_tanh(float x) {
    const float ax = fabsf(x);
    const float t  = __expf(-2.0f * ax);
    const float r  = (1.0f - t) * __builtin_amdgcn_rcpf(1.0f + t);
    return copysignf(r, x);
}

// ---------------- features fp32 -> bf16 -------------------------------------
__global__ __launch_bounds__(256) void convert_feat_kernel(
    const float* __restrict__ feat, ushort_t* __restrict__ featb) {
    const size_t idx = ((size_t)blockIdx.x * 256 + threadIdx.x) * 8;
    const float4 f0 = *(const float4*)(feat + idx);
    const float4 f1 = *(const float4*)(feat + idx + 4);
    *(u64*)(featb + idx)     = pack4(f0);
    *(u64*)(featb + idx + 4) = pack4(f1);
}

// ---------------- W1 transpose + bf16 convert: [K][N] fp32 -> [N][K] bf16 ---
__global__ __launch_bounds__(256) void transpose_w1_kernel(
    const float* __restrict__ w1, ushort_t* __restrict__ w1t) {
    __shared__ ushort_t tile[64][65];
    const int k0 = blockIdx.x * 64, n0 = blockIdx.y * 64;
    const int tr = threadIdx.x >> 6;   // 0..3
    const int tc = threadIdx.x & 63;   // 0..63
#pragma unroll
    for (int i = 0; i < 16; i++) {
        int r = i * 4 + tr;
        tile[tc][r] = f2b(w1[(size_t)(k0 + r) * 1024 + n0 + tc]);
    }
    __syncthreads();
#pragma unroll
    for (int i = 0; i < 16; i++) {
        int r = i * 4 + tr;
        w1t[(size_t)(n0 + r) * 1024 + k0 + tc] = tile[r][tc];
    }
}

// ---------------- proj_h = hidden @ W2 + W2_b + W1_b ------------------------
__global__ __launch_bounds__(256) void projh_kernel(
    const float* __restrict__ hidden, const float* __restrict__ w2,
    const float* __restrict__ w2b, const float* __restrict__ w1b,
    float* __restrict__ ph) {
    const int b  = blockIdx.y;
    const int al = threadIdx.x & 63;
    const int eg = threadIdx.x >> 6;            // 0..3
    const int a  = blockIdx.x * 64 + al;
    const float* h = hidden + b * 1024;
    float sum = 0.f;
    const int e0 = eg * 256;
#pragma unroll 8
    for (int e = e0; e < e0 + 256; e++)
        sum += h[e] * w2[(size_t)e * 1024 + a];
    __shared__ float red[256];
    red[threadIdx.x] = sum;
    __syncthreads();
    if (threadIdx.x < 64)
        ph[b * 1024 + a] = w2b[a] + w1b[a] + red[al] + red[al + 64] +
                           red[al + 128] + red[al + 192];
}

// ---------------- main GEMM (m97 structure + XOR swizzle + XCD remap) -------
// tile 128x128, BK=64, 256 threads (4 waves, each 64x64 = 4x4 MFMA tiles)
#define LOG2E2 2.885390082f   // 2/ln(2): e^{2x} = 2^{x*LOG2E2}

__global__ __launch_bounds__(256) void gemm_scores_bf16_kernel(
    const ushort_t* __restrict__ featb,  // [M][1024] bf16
    const ushort_t* __restrict__ w1t,    // [N][1024] bf16
    const float* __restrict__ ph,        // [B][1024] combined bias
    const float* __restrict__ vw,        // [1024]
    float* __restrict__ part) {          // [16][M] fp32 partial scores
    __shared__ ushort_t As[128 * 64];
    __shared__ ushort_t Bs[128 * 64];
    __shared__ float cbias[128];
    __shared__ float vvw[128];

    const int tid = threadIdx.x;
    const int lid = blockIdx.y * 8 + blockIdx.x;     // HW linear id, x fastest
    const int c   = lid & 7;
    const int rr  = lid >> 3;
    const int mt  = (rr >> 3) * 8 + c;               // m-tile 0..511
    const int nt  = rr & 7;                          // n-tile 0..7
    const int n0 = nt * 128;
    const int m0 = mt * 128;
    const int b  = m0 >> 10;             // L=1024, BM=128 -> one b per block

    if (tid < 128) {
        cbias[tid] = ph[(b << 10) + n0 + tid];
        vvw[tid]   = vw[n0 + tid];
    }

    const int wave = tid >> 6;
    const int lane = tid & 63;
    const int wr = (wave >> 1) * 64;
    const int wc = (wave & 1) * 64;
    const int q  = lane >> 4;
    const int l15 = lane & 15;

    floatx4 acc[4][4] = {};

    // staging: lane i -> LDS row seg*8+(i>>3), LDS block i&7;
    // global block loaded = (i&7)^(i>>3)  => LDS blk b holds glob blk b^(r&7)
    const int srow = lane >> 3;                          // 0..7
    const int scol = ((lane & 7) ^ srow) << 3;           // swizzled, x8 ushorts

    const ushort_t* aBase = featb + (size_t)m0 * 1024;
    const ushort_t* bBase = w1t  + (size_t)n0 * 1024;

    // Precompute all 16 swizzled LDS read offsets (loop-invariant over kt):
    // frag at k-half h (ks = h*32) reads 16B-block g = h*4 + q of row r,
    // stored at LDS block g^(r&7).
    int aoff[4][2], boff[4][2];
#pragma unroll
    for (int t = 0; t < 4; t++) {
        const int ra = wr + t * 16 + l15;
        const int rb = wc + t * 16 + l15;
        aoff[t][0] = ra * 64 + (((q    ) ^ (ra & 7)) << 3);
        aoff[t][1] = ra * 64 + (((q + 4) ^ (ra & 7)) << 3);
        boff[t][0] = rb * 64 + (((q    ) ^ (rb & 7)) << 3);
        boff[t][1] = rb * 64 + (((q + 4) ^ (rb & 7)) << 3);
    }

    for (int kt = 0; kt < 1024; kt += 64) {
#pragma unroll
        for (int p = 0; p < 4; p++) {
            const int seg = wave * 4 + p;            // 0..15
            const int row = seg * 8 + srow;
            gload_lds16(aBase + (size_t)row * 1024 + kt + scol, As + seg * 512);
            gload_lds16(bBase + (size_t)row * 1024 + kt + scol, Bs + seg * 512);
        }
        __syncthreads();
#pragma unroll
        for (int h = 0; h < 2; h++) {
            bf16x8 af[4], bfr[4];
#pragma unroll
            for (int t = 0; t < 4; t++) af[t]  = *(const bf16x8*)&As[aoff[t][h]];
#pragma unroll
            for (int t = 0; t < 4; t++) bfr[t] = *(const bf16x8*)&Bs[boff[t][h]];
#pragma unroll
            for (int tm = 0; tm < 4; tm++)
#pragma unroll
                for (int tn = 0; tn < 4; tn++)
                    acc[tm][tn] = __builtin_amdgcn_mfma_f32_16x16x32_bf16(
                        af[tm], bfr[tn], acc[tm][tn], 0, 0, 0);
        }
        __syncthreads();
    }

    // Epilogue: C/D layout col=lane&15, row=quad*4+reg (measured m89/m91).
    // sum_col tanh(x)*v = sum(v) - 2*sum(v/(e^{2x}+1)); e^{2x}=2^(x*2/ln2).
    // 5 VALU/element, branch-free, exact saturation (e=inf -> rcp=0).
    float vv[4], cbk[4];
    float sum_vvw = 0.f;
#pragma unroll
    for (int tn = 0; tn < 4; tn++) {
        const int col = wc + tn * 16 + l15;
        vv[tn]  = vvw[col];
        cbk[tn] = LOG2E2 * cbias[col];
        sum_vvw += vv[tn];
    }
    const int slot = nt * 2 + (wave & 1);
#pragma unroll
    for (int tm = 0; tm < 4; tm++) {
#pragma unroll
        for (int r = 0; r < 4; r++) {
            const int row = wr + tm * 16 + q * 4 + r;
            float s2 = 0.f;
#pragma unroll
            for (int tn = 0; tn < 4; tn++) {
                const float arg = fmaf(LOG2E2, acc[tm][tn][r], cbk[tn]);
                const float e   = __builtin_amdgcn_exp2f(arg);
                s2 = fmaf(__builtin_amdgcn_rcpf(1.0f + e), vv[tn], s2);
            }
            float s = fmaf(-2.0f, s2, sum_vvw);
            s += __shfl_xor(s, 1);
            s += __shfl_xor(s, 2);
            s += __shfl_xor(s, 4);
            s += __shfl_xor(s, 8);
            if (l15 == 0) part[slot * 65536 + m0 + row] = s;
        }
    }
}

// ---------------- softmax over L per b (sums 16 partials/row) ---------------
__global__ __launch_bounds__(256) void softmax_kernel(
    const float* __restrict__ part, float* __restrict__ alpha) {
    const int b = blockIdx.x;
    const int tid = threadIdx.x;
    __shared__ float red[256];
    float v[4];
    float mx = -1e30f;
#pragma unroll
    for (int i = 0; i < 4; i++) {
        const int m = b * 1024 + tid + i * 256;
        float s = 0.f;
#pragma unroll
        for (int nb = 0; nb < 16; nb++) s += part[nb * 65536 + m];
        v[i] = s;
        mx = fmaxf(mx, s);
    }
    red[tid] = mx; __syncthreads();
    for (int s = 128; s > 0; s >>= 1) {
        if (tid < s) red[tid] = fmaxf(red[tid], red[tid + s]);
        __syncthreads();
    }
    mx = red[0]; __syncthreads();
    float sum = 0.f;
#pragma unroll
    for (int i = 0; i < 4; i++) { v[i] = __expf(v[i] - mx); sum += v[i]; }
    red[tid] = sum; __syncthreads();
    for (int s = 128; s > 0; s >>= 1) {
        if (tid < s) red[tid] += red[tid + s];
        __syncthreads();
    }
    const float inv = 1.0f / red[0];
#pragma unroll
    for (int i = 0; i < 4; i++)
        alpha[b * 1024 + tid + i * 256] = v[i] * inv;
}

// ---------------- context = alpha^T @ featb (bf16 feat, halves traffic) -----
__global__ __launch_bounds__(1024) void context_bf16_kernel(
    const float* __restrict__ alpha, const ushort_t* __restrict__ featb,
    float* __restrict__ ctx) {
    const int b  = blockIdx.y;
    const int el = threadIdx.x & 63;               // e4 lane
    const int lg = threadIdx.x >> 6;               // 0..15
    const int e  = blockIdx.x * 256 + el * 4;
    const ushort_t* fb = featb + ((size_t)b << 20) + e;
    const float* ab = alpha + b * 1024;
    floatx4 acc = {};
    const int l0 = lg * 64;
#pragma unroll 4
    for (int l = l0; l < l0 + 64; l++) {
        const float a = ab[l];
        const ushort4 u = *(const ushort4*)(fb + (size_t)l * 1024);
        acc[0] = fmaf(a, b2f(u.x), acc[0]);
        acc[1] = fmaf(a, b2f(u.y), acc[1]);
        acc[2] = fmaf(a, b2f(u.z), acc[2]);
        acc[3] = fmaf(a, b2f(u.w), acc[3]);
    }
    __shared__ floatx4 red[16 * 64];
    red[lg * 64 + el] = acc;
    __syncthreads();
#pragma unroll
    for (int s = 8; s > 0; s >>= 1) {
        if (lg < s) red[lg * 64 + el] += red[(lg + s) * 64 + el];
        __syncthreads();
    }
    if (lg == 0)
        *(floatx4*)(ctx + b * 1024 + e) = red[el];
}

// ---------------- context fp32 (fallback path only) -------------------------
__global__ __launch_bounds__(1024) void context_kernel(
    const float* __restrict__ alpha, const float* __restrict__ feat,
    float* __restrict__ ctx) {
    const int b  = blockIdx.y;
    const int el = threadIdx.x & 63;
    const int lg = threadIdx.x >> 6;
    const int e  = blockIdx.x * 256 + el * 4;
    const float* fb = feat + (size_t)b * 1024 * 1024;
    const float* ab = alpha + b * 1024;
    floatx4 acc = {};
    const int l0 = lg * 64;
#pragma unroll 4
    for (int l = l0; l < l0 + 64; l++) {
        const float a = ab[l];
        const floatx4 f = *(const floatx4*)(fb + (size_t)l * 1024 + e);
        acc += a * f;
    }
    __shared__ floatx4 red[16 * 64];
    red[lg * 64 + el] = acc;
    __syncthreads();
#pragma unroll
    for (int s = 8; s > 0; s >>= 1) {
        if (lg < s) red[lg * 64 + el] += red[(lg + s) * 64 + el];
        __syncthreads();
    }
    if (lg == 0)
        *(floatx4*)(ctx + b * 1024 + e) = red[el];
}

// ---------------- fallback GEMM (fp32 A staging, padded LDS) ----------------
#define KP 72
__global__ __launch_bounds__(256) void gemm_scores_f32_kernel(
    const float* __restrict__ feat, const ushort_t* __restrict__ w1t,
    const float* __restrict__ ph, const float* __restrict__ vw,
    float* __restrict__ part) {
    __shared__ ushort_t As[128 * KP];
    __shared__ ushort_t Bs[128 * KP];
    __shared__ float cbias[128];
    __shared__ float vvw[128];
    const int tid = threadIdx.x;
    const int nt = blockIdx.x, n0 = nt * 128, m0 = blockIdx.y * 128;
    const int b = m0 >> 10;
    if (tid < 128) { cbias[tid] = ph[(b << 10) + n0 + tid]; vvw[tid] = vw[n0 + tid]; }
    const int wave = tid >> 6, lane = tid & 63;
    const int wr = (wave >> 1) * 64, wc = (wave & 1) * 64;
    const int q = lane >> 4, l15 = lane & 15;
    floatx4 acc[4][4] = {};
    const int arow = tid >> 4, acol = (tid & 15) * 4;
    const int brow = tid >> 3, bcol = (tid & 7) * 8;
    const float* aptr = feat + (size_t)m0 * 1024;
    const ushort_t* bptr = w1t + (size_t)n0 * 1024;
    for (int kt = 0; kt < 1024; kt += 64) {
#pragma unroll
        for (int p = 0; p < 8; p++) {
            int r = p * 16 + arow;
            const float4 f = *(const float4*)(aptr + (size_t)r * 1024 + kt + acol);
            *(u64*)&As[r * KP + acol] = pack4(f);
        }
#pragma unroll
        for (int p = 0; p < 4; p++) {
            int r = p * 32 + brow;
            *(uint4*)&Bs[r * KP + bcol] =
                *(const uint4*)(bptr + (size_t)r * 1024 + kt + bcol);
        }
        __syncthreads();
#pragma unroll
        for (int ks = 0; ks < 64; ks += 32) {
            bf16x8 af[4], bfr[4];
#pragma unroll
            for (int t = 0; t < 4; t++)
                af[t] = *(const bf16x8*)&As[(wr + t * 16 + l15) * KP + ks + q * 8];
#pragma unroll
            for (int t = 0; t < 4; t++)
                bfr[t] = *(const bf16x8*)&Bs[(wc + t * 16 + l15) * KP + ks + q * 8];
#pragma unroll
            for (int tm = 0; tm < 4; tm++)
#pragma unroll
                for (int tn = 0; tn < 4; tn++)
                    acc[tm][tn] = __builtin_amdgcn_mfma_f32_16x16x32_bf16(
                        af[tm], bfr[tn], acc[tm][tn], 0, 0, 0);
        }
        __syncthreads();
    }
    const int slot = nt * 2 + (wave & 1);
#pragma unroll
    for (int tm = 0; tm < 4; tm++) {
#pragma unroll
        for (int r = 0; r < 4; r++) {
            const int row = wr + tm * 16 + q * 4 + r;
            float s = 0.f;
#pragma unroll
            for (int tn = 0; tn < 4; tn++) {
                const int col = wc + tn * 16 + l15;
                s += fast_tanh(acc[tm][tn][r] + cbias[col]) * vvw[col];
            }
            s += __shfl_xor(s, 1);
            s += __shfl_xor(s, 2);
            s += __shfl_xor(s, 4);
            s += __shfl_xor(s, 8);
            if (l15 == 0) part[slot * 65536 + m0 + row] = s;
        }
    }
}

// ---------------- launcher --------------------------------------------------
extern "C" void kernel_launch(void* const* d_in, const int* in_sizes, int n_in,
                              void* d_out, int out_size, void* d_ws, size_t ws_size,
                              hipStream_t stream) {
    const float* feat = (const float*)d_in[0];   // [64,1024,1024]
    const float* hid  = (const float*)d_in[1];   // [64,1024]
    const float* w1w  = (const float*)d_in[2];   // [1024,1024]
    const float* w1b  = (const float*)d_in[3];   // [1024]
    const float* w2w  = (const float*)d_in[4];   // [1024,1024]
    const float* w2b  = (const float*)d_in[5];   // [1024]
    const float* vw   = (const float*)d_in[6];   // [1024]
    // d_in[7] = V_b: cancels in softmax -> unused

    const size_t FEATB_BYTES = (size_t)64 * 1024 * 1024 * 2;  // 128 MB
    const size_t W1T_BYTES   = (size_t)1024 * 1024 * 2;       // 2 MB
    const size_t PH_BYTES    = (size_t)64 * 1024 * 4;         // 256 KB
    const size_t PART_BYTES  = (size_t)16 * 65536 * 4;        // 4 MB
    const bool   big_ws = ws_size >= FEATB_BYTES + W1T_BYTES + PH_BYTES + PART_BYTES;
    if (!big_ws && ws_size < W1T_BYTES + PH_BYTES + PART_BYTES) return;

    char* ws = (char*)d_ws;
    ushort_t* featb = (ushort_t*)ws;
    size_t off = big_ws ? FEATB_BYTES : 0;
    ushort_t* w1t  = (ushort_t*)(ws + off);
    float* ph      = (float*)(ws + off + W1T_BYTES);
    float* part    = (float*)(ws + off + W1T_BYTES + PH_BYTES);

    float* alpha = (float*)d_out;           // [64,1024]
    float* ctx   = alpha + 64 * 1024;       // [64,1024]

    transpose_w1_kernel<<<dim3(16, 16), 256, 0, stream>>>(w1w, w1t);
    projh_kernel<<<dim3(16, 64), 256, 0, stream>>>(hid, w2w, w2b, w1b, ph);
    if (big_ws) {
        convert_feat_kernel<<<32768, 256, 0, stream>>>(feat, featb);
        gemm_scores_bf16_kernel<<<dim3(8, 512), 256, 0, stream>>>(
            featb, w1t, ph, vw, part);
        softmax_kernel<<<64, 256, 0, stream>>>(part, alpha);
        context_bf16_kernel<<<dim3(4, 64), 1024, 0, stream>>>(alpha, featb, ctx);
    } else {
        gemm_scores_f32_kernel<<<dim3(8, 512), 256, 0, stream>>>(
            feat, w1t, ph, vw, part);
        softmax_kernel<<<64, 256, 0, stream>>>(part, alpha);
        context_kernel<<<dim3(4, 64), 1024, 0, stream>>>(alpha, feat, ctx);
    }
}